// Round 8
// baseline (355.605 us; speedup 1.0000x reference)
//
#include <hip/hip_runtime.h>
#include <hip/hip_bf16.h>

// Problem constants (fixed by the reference)
#define B_  256
#define T_  72
#define N_  5
#define F_  10
#define D_  128
#define HH_ 4
#define CC_ 32
#define FF_ 256
#define BT_ (B_*T_)   // 18432
#define E2MAX 32

// ---------------- ws layout (float offsets) ----------------
#define WS_Z    256
#define WS_QKV  (WS_Z + BT_*D_)
#define WS_OBUF (WS_QKV + BT_*3*D_)
#define WS_WBF  (WS_OBUF + BT_*D_)      // bf16 weight region

// bf16 weight offsets (in shorts, from WS_WBF base)
#define WOFF_QKV(i)  ((i)*49152)                 // [384][128]
#define WOFF_O(i)    (147456 + (i)*16384)        // [128][128]
#define WOFF_FF1(i)  (196608 + (i)*32768)        // [256][128]
#define WOFF_FF2(i)  (294912 + (i)*32768)        // [128][256]
#define WOFF_GATW    393216                      // [128][64]

// ---------------- mega-kernel LDS carve (bytes) ----------------
#define MZF_OFF   0          // float [72][132]           38,016
#define MSB_OFF   38016      // short [128][128] (weights; P strips & h1 alias) 32,768
#define MSQ_OFF   70784      // short [80][136]           21,760  (s_f part 1)
#define MSK_OFF   92544      // short [80][136]           21,760  (s_f part 2)
#define MVT_OFF   114304     // short [128][104]          26,624  (z1 bf16 aliases)
#define MOB_OFF   140928     // short [80][136]           21,760
#define MSMEM_BYTES 162688

typedef __attribute__((ext_vector_type(8))) short bf16x8;
typedef __attribute__((ext_vector_type(4))) float f32x4;

__device__ __forceinline__ unsigned short bf16_rne(float x) {
    unsigned u = __float_as_uint(x);
    unsigned r = (u + 0x7FFFu + ((u >> 16) & 1u)) >> 16;
    return (unsigned short)r;
}
__device__ __forceinline__ unsigned bf16pk(float a, float b) {
    return (unsigned)bf16_rne(a) | ((unsigned)bf16_rne(b) << 16);
}
__device__ __forceinline__ float bf2f(short s) {
    return __uint_as_float(((unsigned)(unsigned short)s) << 16);
}
// convert 8 consecutive fp32 (16B-aligned) to bf16x8
__device__ __forceinline__ bf16x8 cvt8(const float* p) {
    float4 a = *(const float4*)p;
    float4 b = *(const float4*)(p + 4);
    unsigned u[4] = {bf16pk(a.x, a.y), bf16pk(a.z, a.w), bf16pk(b.x, b.y), bf16pk(b.z, b.w)};
    return *(bf16x8*)u;
}

// ---------------------------------------------------------------------------
__global__ void setup_kernel(const int* __restrict__ ei, float* __restrict__ ws, int E) {
    if (threadIdx.x != 0 || blockIdx.x != 0) return;
    int* wsi = (int*)ws;
    const int N = N_;
    int E2 = E + N;
    int src2[E2MAX], dst2[E2MAX];
    for (int e = 0; e < E; ++e) { src2[e] = ei[e]; dst2[e] = ei[E + e]; }
    for (int n = 0; n < N; ++n) { src2[E + n] = n; dst2[E + n] = n; }
    float A[N_ * N_];
    for (int i = 0; i < N * N; ++i) A[i] = 0.f;
    for (int e = 0; e < E2; ++e) A[dst2[e] * N + src2[e]] += 1.f;
    float dinv[N_];
    for (int n = 0; n < N; ++n) {
        float s = 0.f;
        for (int j = 0; j < N; ++j) s += A[n * N + j];
        dinv[n] = (s > 0.f) ? rsqrtf(s) : 0.f;
    }
    for (int n = 0; n < N; ++n)
        for (int j = 0; j < N; ++j)
            ws[n * N + j] = dinv[n] * A[n * N + j] * dinv[j];
    int cnt[N_];
    for (int n = 0; n < N; ++n) cnt[n] = 0;
    for (int e = 0; e < E2; ++e) cnt[dst2[e]]++;
    int off = 0;
    for (int n = 0; n < N; ++n) { wsi[96 + n] = off; off += cnt[n]; }
    wsi[96 + N] = off;
    int cur[N_];
    for (int n = 0; n < N; ++n) cur[n] = wsi[96 + n];
    for (int e = 0; e < E2; ++e) wsi[104 + cur[dst2[e]]++] = e;
    for (int e = 0; e < E2; ++e) { wsi[32 + e] = src2[e]; wsi[64 + e] = dst2[e]; }
}

// ---------------------------------------------------------------------------
// Weight prep: transpose R x C fp32 -> [C][R] bf16 into ws.
__global__ __launch_bounds__(256) void prep_kernel(
    const float* __restrict__ tw_qkv, const float* __restrict__ tw_o,
    const float* __restrict__ w_ff1, const float* __restrict__ w_ff2,
    const float* __restrict__ gat_w, short* __restrict__ wbf)
{
    __shared__ float s_t[64][65];
    const int tid = threadIdx.x;
    int t = blockIdx.x;
    const float* src; short* dst; int R, C, tr, tc;
    if (t >= 96) { int q = t - 96; src = gat_w; dst = wbf + WOFF_GATW; R = 64; C = 128; tr = 0; tc = q; }
    else {
        int layer = t / 32, r32 = t % 32;
        if (r32 < 12)      { src = tw_qkv + layer * (128*384); dst = wbf + WOFF_QKV(layer); R = 128; C = 384; tr = r32 / 6;  tc = r32 % 6; }
        else if (r32 < 16) { int q = r32 - 12; src = tw_o + layer * 16384; dst = wbf + WOFF_O(layer);  R = 128; C = 128; tr = q >> 1; tc = q & 1; }
        else if (r32 < 24) { int q = r32 - 16; src = w_ff1 + layer * 32768; dst = wbf + WOFF_FF1(layer); R = 128; C = 256; tr = q >> 2; tc = q & 3; }
        else               { int q = r32 - 24; src = w_ff2 + layer * 32768; dst = wbf + WOFF_FF2(layer); R = 256; C = 128; tr = q >> 1; tc = q & 1; }
    }
    #pragma unroll
    for (int it = 0; it < 16; ++it) {
        int e = it * 256 + tid;
        int r = e >> 6, c = e & 63;
        s_t[r][c] = src[(size_t)(tr*64 + r) * C + tc*64 + c];
    }
    __syncthreads();
    #pragma unroll
    for (int it = 0; it < 16; ++it) {
        int e = it * 256 + tid;
        int c = e >> 6, r = e & 63;
        dst[(size_t)(tc*64 + c) * R + tr*64 + r] = (short)bf16_rne(s_t[r][c]);
    }
}

// ---------------------------------------------------------------------------
// MFMA helpers: swizzled LDS B tiles
__device__ __forceinline__ bf16x8 ld_frag(const short* s, int row, int kbase, int ldk) {
    return *(const bf16x8*)&s[row * ldk + (kbase ^ ((row & 7) << 3))];
}
__device__ __forceinline__ void stage_b(short* s_b, const short* __restrict__ src, int tid) {
    const uint4* s4 = (const uint4*)src;
    #pragma unroll
    for (int it = 0; it < 8; ++it) {
        int c = it * 256 + tid;
        int row = c >> 4, ke = (c & 15) * 8;
        *(uint4*)&s_b[row * 128 + (ke ^ ((row & 7) << 3))] = s4[c];
    }
}

// ---------------------------------------------------------------------------
// G1: x -> GCN(tanh) -> h = gcn @ gat_w (MFMA) -> h (bf16 global), a_s/a_d (global)
__global__ __launch_bounds__(256) void gcn_h_mfma(
    const float* __restrict__ x, const float* __restrict__ gcn_w, const float* __restrict__ gcn_b,
    const float* __restrict__ a_src, const float* __restrict__ a_dst,
    const float* __restrict__ ws, const short* __restrict__ gwT,
    short* __restrict__ hbuf, float* __restrict__ asb, float* __restrict__ adb)
{
    __shared__ float s_x[16 * 50];
    __shared__ float s_an[25];
    __shared__ short s_gcn[80 * 64];

    const int tid = threadIdx.x;
    const int tok0 = blockIdx.x * 16;

    for (int i = tid; i < 16 * 50; i += 256) s_x[i] = x[(size_t)tok0 * 50 + i];
    if (tid < 25) s_an[tid] = ws[tid];
    __syncthreads();

    #pragma unroll
    for (int it = 0; it < 2; ++it) {
        int idx = it * 256 + tid;
        int tl = idx >> 5, kp = idx & 31;
        int k0 = kp * 2;
        float w0[F_], w1[F_];
        #pragma unroll
        for (int f = 0; f < F_; ++f) { w0[f] = gcn_w[f * 64 + k0]; w1[f] = gcn_w[f * 64 + k0 + 1]; }
        float b0 = gcn_b[k0], b1 = gcn_b[k0 + 1];
        float xw0[N_], xw1[N_];
        #pragma unroll
        for (int n = 0; n < N_; ++n) {
            float a0 = b0, a1 = b1;
            #pragma unroll
            for (int f = 0; f < F_; ++f) {
                float xv = s_x[tl * 50 + n * 10 + f];
                a0 += xv * w0[f]; a1 += xv * w1[f];
            }
            xw0[n] = a0; xw1[n] = a1;
        }
        #pragma unroll
        for (int n = 0; n < N_; ++n) {
            float s0 = 0.f, s1 = 0.f;
            #pragma unroll
            for (int j = 0; j < N_; ++j) { float an = s_an[n * 5 + j]; s0 += an * xw0[j]; s1 += an * xw1[j]; }
            float e0 = __expf(2.f * fabsf(s0)), e1 = __expf(2.f * fabsf(s1));
            float t0 = copysignf(1.f - 2.f / (e0 + 1.f), s0);
            float t1 = copysignf(1.f - 2.f / (e1 + 1.f), s1);
            int row = tl * 5 + n;
            *(unsigned*)&s_gcn[row * 64 + (k0 ^ ((row & 7) << 3))] = bf16pk(t0, t1);
        }
    }
    __syncthreads();

    const int w = tid >> 6, lane = tid & 63;
    const int c = lane & 15, g = lane >> 4;
    const int kf = g * 8;
    bf16x8 bfr[2][2];
    #pragma unroll
    for (int nn = 0; nn < 2; ++nn)
        #pragma unroll
        for (int k0 = 0; k0 < 2; ++k0)
            bfr[nn][k0] = *(const bf16x8*)&gwT[(w * 32 + nn * 16 + c) * 64 + k0 * 32 + kf];
    const float as0 = a_src[w * 32 + c],      as1 = a_src[w * 32 + 16 + c];
    const float ad0 = a_dst[w * 32 + c],      ad1 = a_dst[w * 32 + 16 + c];
    #pragma unroll
    for (int m = 0; m < 5; ++m) {
        bf16x8 af0 = ld_frag(s_gcn, m * 16 + c, kf, 64);
        bf16x8 af1 = ld_frag(s_gcn, m * 16 + c, 32 + kf, 64);
        f32x4 a0 = {0,0,0,0}, a1 = {0,0,0,0};
        a0 = __builtin_amdgcn_mfma_f32_16x16x32_bf16(af0, bfr[0][0], a0, 0, 0, 0);
        a0 = __builtin_amdgcn_mfma_f32_16x16x32_bf16(af1, bfr[0][1], a0, 0, 0, 0);
        a1 = __builtin_amdgcn_mfma_f32_16x16x32_bf16(af0, bfr[1][0], a1, 0, 0, 0);
        a1 = __builtin_amdgcn_mfma_f32_16x16x32_bf16(af1, bfr[1][1], a1, 0, 0, 0);
        float ps[4], pd[4];
        #pragma unroll
        for (int i = 0; i < 4; ++i) {
            int row = m * 16 + g * 4 + i;
            size_t gr = (size_t)(tok0 * 5 + row) * 128;
            hbuf[gr + w * 32 + c]      = (short)bf16_rne(a0[i]);
            hbuf[gr + w * 32 + 16 + c] = (short)bf16_rne(a1[i]);
            ps[i] = a0[i] * as0 + a1[i] * as1;
            pd[i] = a0[i] * ad0 + a1[i] * ad1;
        }
        #pragma unroll
        for (int mm = 1; mm < 16; mm <<= 1)
            #pragma unroll
            for (int i = 0; i < 4; ++i) { ps[i] += __shfl_xor(ps[i], mm); pd[i] += __shfl_xor(pd[i], mm); }
        if (c == 0) {
            #pragma unroll
            for (int i = 0; i < 4; ++i) {
                int row = m * 16 + g * 4 + i;
                asb[(size_t)(tok0 * 5 + row) * 4 + w] = ps[i];
                adb[(size_t)(tok0 * 5 + row) * 4 + w] = pd[i];
            }
        }
    }
}

// ---------------------------------------------------------------------------
// G2: alpha softmax + aggregate + gat_b + LN + mean + PE -> z
__global__ __launch_bounds__(256) void gat_agg(
    const short* __restrict__ hbuf, const float* __restrict__ asb, const float* __restrict__ adb,
    const float* __restrict__ gat_b, const float* __restrict__ gln_g, const float* __restrict__ gln_b,
    const float* __restrict__ ws, float* __restrict__ z, int E2)
{
    __shared__ int   s_src[E2MAX], s_csr_off[N_ + 1], s_csr_e[E2MAX];
    __shared__ float s_alpha[4][E2MAX][4];
    __shared__ short s_h[4 * 5 * 128];

    const int tid = threadIdx.x;
    const int wv = tid >> 6, lane = tid & 63;
    const int tok = blockIdx.x * 4 + wv;
    const int* wsi = (const int*)ws;

    if (tid < E2) { s_src[tid] = wsi[32 + tid]; s_csr_e[tid] = wsi[104 + tid]; }
    if (tid < N_ + 1) s_csr_off[tid] = wsi[96 + tid];
    {
        const uint4* hb4 = (const uint4*)(hbuf + (size_t)blockIdx.x * 4 * 5 * 128);
        uint4* sh4 = (uint4*)s_h;
        #pragma unroll
        for (int it = 0; it < 2; ++it) {
            int i = it * 256 + tid;
            if (i < 320) sh4[i] = hb4[i];
        }
    }
    __syncthreads();

    if (lane < 20) {
        int dn = lane >> 2, head = lane & 3;
        int j0 = s_csr_off[dn], j1 = s_csr_off[dn + 1];
        float adv = adb[(size_t)(tok * 5 + dn) * 4 + head];
        float mx = -1e30f;
        for (int j = j0; j < j1; ++j) {
            int e = s_csr_e[j];
            float ev = asb[(size_t)(tok * 5 + s_src[e]) * 4 + head] + adv;
            ev = ev > 0.f ? ev : 0.2f * ev;
            mx = fmaxf(mx, ev);
        }
        float den = 0.f;
        for (int j = j0; j < j1; ++j) {
            int e = s_csr_e[j];
            float ev = asb[(size_t)(tok * 5 + s_src[e]) * 4 + head] + adv;
            ev = ev > 0.f ? ev : 0.2f * ev;
            float ex = __expf(ev - mx);
            den += ex;
            s_alpha[wv][e][head] = ex;
        }
        float r = 1.f / den;
        for (int j = j0; j < j1; ++j) s_alpha[wv][s_csr_e[j]][head] *= r;
    }
    __syncthreads();

    const int h0 = lane >> 5, h1 = 2 + (lane >> 5);
    const float gb0 = gat_b[lane],      gb1 = gat_b[lane + 64];
    const float gg0 = gln_g[lane],      gg1 = gln_g[lane + 64];
    const float gB0 = gln_b[lane],      gB1 = gln_b[lane + 64];
    float v0[N_], v1[N_];
    #pragma unroll
    for (int n = 0; n < N_; ++n) {
        float a0 = 0.f, a1 = 0.f;
        int j0 = s_csr_off[n], j1 = s_csr_off[n + 1];
        for (int j = j0; j < j1; ++j) {
            int e = s_csr_e[j];
            int rb = (wv * 5 + s_src[e]) * 128;
            a0 += s_alpha[wv][e][h0] * bf2f(s_h[rb + lane]);
            a1 += s_alpha[wv][e][h1] * bf2f(s_h[rb + lane + 64]);
        }
        v0[n] = a0 + gb0; v1[n] = a1 + gb1;
    }
    float r1[N_], r2[N_];
    #pragma unroll
    for (int n = 0; n < N_; ++n) { r1[n] = v0[n] + v1[n]; r2[n] = v0[n]*v0[n] + v1[n]*v1[n]; }
    #pragma unroll
    for (int mm = 1; mm < 64; mm <<= 1)
        #pragma unroll
        for (int n = 0; n < N_; ++n) { r1[n] += __shfl_xor(r1[n], mm); r2[n] += __shfl_xor(r2[n], mm); }
    float z0 = 0.f, z1 = 0.f;
    #pragma unroll
    for (int n = 0; n < N_; ++n) {
        float mu = r1[n] * (1.f / D_);
        float var = r2[n] * (1.f / D_) - mu * mu;
        float rstd = rsqrtf(var + 1e-5f);
        z0 += (v0[n] - mu) * rstd * gg0 + gB0;
        z1 += (v1[n] - mu) * rstd * gg1 + gB1;
    }
    z0 *= (1.f / N_); z1 *= (1.f / N_);
    const float cpe = -9.210340371976184f / (float)D_;
    int t = tok % T_;
    float dv0 = __expf((float)(lane & ~1) * cpe);
    float dv1 = __expf((float)((lane + 64) & ~1) * cpe);
    float ang0 = (float)t * dv0, ang1 = (float)t * dv1;
    z0 += (lane & 1) ? __cosf(ang0) : __sinf(ang0);
    z1 += (lane & 1) ? __cosf(ang1) : __sinf(ang1);
    z[(size_t)tok * D_ + lane] = z0;
    z[(size_t)tok * D_ + 64 + lane] = z1;
}

// ---------------------------------------------------------------------------
// MEGA: all 3 transformer layers + 6 heads, one block per batch (grid 256).
// z fp32 resident in LDS; weights staged per phase; Q/K/V^T/P/obuf/z1 in LDS.
__global__ __launch_bounds__(256, 1) void layers_fused(
    const float* __restrict__ zg, const short* __restrict__ wbf,
    const float* __restrict__ tb_qkv, const float* __restrict__ tb_o,
    const float* __restrict__ ln1_g, const float* __restrict__ ln1_b,
    const float* __restrict__ b_ff1, const float* __restrict__ b_ff2,
    const float* __restrict__ ln2_g, const float* __restrict__ ln2_b,
    const float* __restrict__ hw1, const float* __restrict__ hb1,
    const float* __restrict__ hw2, const float* __restrict__ hb2,
    float* __restrict__ out)
{
    extern __shared__ char smem[];
    float* s_zf = (float*)(smem + MZF_OFF);          // [72][132]
    short* s_b  = (short*)(smem + MSB_OFF);          // [128][128] swizzled weights
    short* s_q  = (short*)(smem + MSQ_OFF);          // [80][136]
    short* s_k  = (short*)(smem + MSK_OFF);          // [80][136]
    short* s_vt = (short*)(smem + MVT_OFF);          // [128][104]; z1 bf16 aliases [80][136]
    short* s_ob = (short*)(smem + MOB_OFF);          // [80][136]
    short* s_f  = s_q;                               // [80][264] (q+k region)
    short* s_z1 = s_vt;                              // [80][136]

    const int tid = threadIdx.x;
    const int w = tid >> 6, lane = tid & 63;
    const int c = lane & 15, g = lane >> 4;
    const int kf = g * 8;
    const int b = blockIdx.x;

    // ---- load z (fp32) -> s_zf; zero s_vt tail keys once (NaN-pattern guard)
    for (int idx = tid; idx < 72 * 128; idx += 256) {
        int r = idx >> 7, col = idx & 127;
        s_zf[r * 132 + col] = zg[(size_t)(b * T_ + r) * D_ + col];
    }
    for (int idx = tid; idx < 128 * 32; idx += 256) {
        int ch = idx >> 5, key = 72 + (idx & 31);
        s_vt[ch * 104 + key] = 0;
    }
    __syncthreads();

    for (int L = 0; L < 3; ++L) {
        const short* Wq = wbf + WOFF_QKV(L);
        const short* Wo = wbf + WOFF_O(L);
        const short* W1 = wbf + WOFF_FF1(L);
        const short* W2 = wbf + WOFF_FF2(L);
        const float* bq = tb_qkv + L * 384;
        const float* bo = tb_o + L * D_;
        const float* g1 = ln1_g + L * D_, *be1 = ln1_b + L * D_;
        const float* b1 = b_ff1 + L * FF_, *b2 = b_ff2 + L * D_;
        const float* g2 = ln2_g + L * D_, *be2 = ln2_b + L * D_;

        // ================= QKV: 3 chunks of 128 cols =================
        for (int ch = 0; ch < 3; ++ch) {
            __syncthreads();
            stage_b(s_b, Wq + ch * 16384, tid);
            __syncthreads();
            // this wave owns n0 = {2w, 2w+1}
            bf16x8 Bf[2][4];
            float bvj[2];
            #pragma unroll
            for (int j = 0; j < 2; ++j) {
                int n0 = w * 2 + j;
                int brow = n0 * 16 + c;
                #pragma unroll
                for (int k0 = 0; k0 < 4; ++k0) Bf[j][k0] = ld_frag(s_b, brow, k0 * 32 + kf, 128);
                bvj[j] = bq[ch * 128 + n0 * 16 + c];
            }
            #pragma unroll
            for (int m = 0; m < 5; ++m) {
                int arow = m * 16 + c;
                bool valid = arow < 72;
                bf16x8 Af[4];
                bf16x8 z8 = {0,0,0,0,0,0,0,0};
                #pragma unroll
                for (int k0 = 0; k0 < 4; ++k0)
                    Af[k0] = valid ? cvt8(&s_zf[arow * 132 + k0 * 32 + kf]) : z8;
                #pragma unroll
                for (int j = 0; j < 2; ++j) {
                    int n0 = w * 2 + j;
                    f32x4 acc = {bvj[j], bvj[j], bvj[j], bvj[j]};
                    #pragma unroll
                    for (int k0 = 0; k0 < 4; ++k0)
                        acc = __builtin_amdgcn_mfma_f32_16x16x32_bf16(Af[k0], Bf[j][k0], acc, 0, 0, 0);
                    int wcol = n0 * 16 + c;
                    #pragma unroll
                    for (int i = 0; i < 4; ++i) {
                        int lrow = m * 16 + g * 4 + i;
                        short v = (short)bf16_rne(acc[i]);
                        if (ch == 0)      s_q[lrow * 136 + wcol] = v;
                        else if (ch == 1) s_k[lrow * 136 + wcol] = v;
                        else              s_vt[wcol * 104 + lrow] = v;
                    }
                }
            }
        }
        __syncthreads();   // q,k,vt visible to all waves

        // ================= ATTENTION: wave w = head w =================
        {
            short* pstrip = s_b + w * 16 * 104;   // per-wave P strip [16][104] (s_b idle)
            for (int t2 = lane; t2 < 16 * 16; t2 += 64) {
                int r = t2 >> 4, col = 80 + (t2 & 15);
                pstrip[r * 104 + col] = 0;
            }
            const float scale = 0.17677669529663687f;
            #pragma unroll
            for (int m = 0; m < 5; ++m) {
                bf16x8 aq = *(const bf16x8*)&s_q[(m * 16 + c) * 136 + w * 32 + kf];
                float ps[5][4], mx[4], den[4];
                #pragma unroll
                for (int i = 0; i < 4; ++i) mx[i] = -1e30f;
                #pragma unroll
                for (int n0 = 0; n0 < 5; ++n0) {
                    bf16x8 bk = *(const bf16x8*)&s_k[(n0 * 16 + c) * 136 + w * 32 + kf];
                    f32x4 z4 = {0,0,0,0};
                    f32x4 accS = __builtin_amdgcn_mfma_f32_16x16x32_bf16(aq, bk, z4, 0, 0, 0);
                    #pragma unroll
                    for (int i = 0; i < 4; ++i) {
                        float s = accS[i] * scale;
                        if (n0 == 4 && c >= 8) s = -1e30f;
                        ps[n0][i] = s;
                        mx[i] = fmaxf(mx[i], s);
                    }
                }
                #pragma unroll
                for (int mm = 1; mm < 16; mm <<= 1)
                    #pragma unroll
                    for (int i = 0; i < 4; ++i) mx[i] = fmaxf(mx[i], __shfl_xor(mx[i], mm));
                #pragma unroll
                for (int i = 0; i < 4; ++i) den[i] = 0.f;
                #pragma unroll
                for (int n0 = 0; n0 < 5; ++n0)
                    #pragma unroll
                    for (int i = 0; i < 4; ++i) { float e = __expf(ps[n0][i] - mx[i]); ps[n0][i] = e; den[i] += e; }
                #pragma unroll
                for (int mm = 1; mm < 16; mm <<= 1)
                    #pragma unroll
                    for (int i = 0; i < 4; ++i) den[i] += __shfl_xor(den[i], mm);
                float rden[4];
                #pragma unroll
                for (int i = 0; i < 4; ++i) rden[i] = 1.f / den[i];
                #pragma unroll
                for (int n0 = 0; n0 < 5; ++n0)
                    #pragma unroll
                    for (int i = 0; i < 4; ++i)
                        pstrip[(g * 4 + i) * 104 + n0 * 16 + c] = (short)bf16_rne(ps[n0][i] * rden[i]);
                // PV (wave-private P strip; compiler orders the LDS RAW)
                f32x4 accO[2] = {{0,0,0,0},{0,0,0,0}};
                #pragma unroll
                for (int kt = 0; kt < 3; ++kt) {
                    bf16x8 ap = *(const bf16x8*)&pstrip[c * 104 + kt * 32 + kf];
                    #pragma unroll
                    for (int n0 = 0; n0 < 2; ++n0) {
                        bf16x8 bv = *(const bf16x8*)&s_vt[(w * 32 + n0 * 16 + c) * 104 + kt * 32 + kf];
                        accO[n0] = __builtin_amdgcn_mfma_f32_16x16x32_bf16(ap, bv, accO[n0], 0, 0, 0);
                    }
                }
                #pragma unroll
                for (int n0 = 0; n0 < 2; ++n0)
                    #pragma unroll
                    for (int i = 0; i < 4; ++i)
                        s_ob[(m * 16 + g * 4 + i) * 136 + w * 32 + n0 * 16 + c] = (short)bf16_rne(accO[n0][i]);
            }
        }
        __syncthreads();   // s_ob visible; P strips dead before weight restaging

        // ================= O-PROJ + LN1 (row-split m = {w, w+4}) =================
        stage_b(s_b, Wo, tid);
        __syncthreads();
        for (int m = w; m < 5; m += 4) {
            bf16x8 Af[4];
            #pragma unroll
            for (int k0 = 0; k0 < 4; ++k0)
                Af[k0] = *(const bf16x8*)&s_ob[(m * 16 + c) * 136 + k0 * 32 + kf];
            f32x4 acc[8];
            #pragma unroll
            for (int n0 = 0; n0 < 8; ++n0) {
                float bv = bo[n0 * 16 + c];
                acc[n0] = (f32x4){bv, bv, bv, bv};
                int brow = n0 * 16 + c;
                #pragma unroll
                for (int k0 = 0; k0 < 4; ++k0) {
                    bf16x8 bfg = ld_frag(s_b, brow, k0 * 32 + kf, 128);
                    acc[n0] = __builtin_amdgcn_mfma_f32_16x16x32_bf16(Af[k0], bfg, acc[n0], 0, 0, 0);
                }
            }
            // residual + LN1
            #pragma unroll
            for (int n0 = 0; n0 < 8; ++n0)
                #pragma unroll
                for (int i = 0; i < 4; ++i) {
                    int row = m * 16 + g * 4 + i;
                    acc[n0][i] += (row < 72) ? s_zf[row * 132 + n0 * 16 + c] : 0.f;
                }
            float s1[4] = {0,0,0,0}, s2[4] = {0,0,0,0};
            #pragma unroll
            for (int n0 = 0; n0 < 8; ++n0)
                #pragma unroll
                for (int i = 0; i < 4; ++i) { float v = acc[n0][i]; s1[i] += v; s2[i] += v * v; }
            #pragma unroll
            for (int mm = 1; mm < 16; mm <<= 1)
                #pragma unroll
                for (int i = 0; i < 4; ++i) { s1[i] += __shfl_xor(s1[i], mm); s2[i] += __shfl_xor(s2[i], mm); }
            #pragma unroll
            for (int i = 0; i < 4; ++i) {
                float mu = s1[i] * (1.f / D_);
                float var = s2[i] * (1.f / D_) - mu * mu;
                float rstd = rsqrtf(var + 1e-5f);
                int row = m * 16 + g * 4 + i;
                #pragma unroll
                for (int n0 = 0; n0 < 8; ++n0) {
                    float v = (acc[n0][i] - mu) * rstd * g1[n0 * 16 + c] + be1[n0 * 16 + c];
                    if (row < 72) s_zf[row * 132 + n0 * 16 + c] = v;   // z1 fp32
                    s_z1[row * 136 + n0 * 16 + c] = (short)bf16_rne(v); // z1 bf16
                }
            }
        }

        // ================= FF1 (col-split, 2 chunks) =================
        for (int ch = 0; ch < 2; ++ch) {
            __syncthreads();
            stage_b(s_b, W1 + ch * 16384, tid);
            __syncthreads();
            bf16x8 Bf[2][4];
            float bvj[2];
            #pragma unroll
            for (int j = 0; j < 2; ++j) {
                int n0 = w * 2 + j;
                int brow = n0 * 16 + c;
                #pragma unroll
                for (int k0 = 0; k0 < 4; ++k0) Bf[j][k0] = ld_frag(s_b, brow, k0 * 32 + kf, 128);
                bvj[j] = b1[ch * 128 + n0 * 16 + c];
            }
            #pragma unroll
            for (int m = 0; m < 5; ++m) {
                bf16x8 Af[4];
                #pragma unroll
                for (int k0 = 0; k0 < 4; ++k0)
                    Af[k0] = *(const bf16x8*)&s_z1[(m * 16 + c) * 136 + k0 * 32 + kf];
                #pragma unroll
                for (int j = 0; j < 2; ++j) {
                    int n0 = w * 2 + j;
                    f32x4 acc = {bvj[j], bvj[j], bvj[j], bvj[j]};
                    #pragma unroll
                    for (int k0 = 0; k0 < 4; ++k0)
                        acc = __builtin_amdgcn_mfma_f32_16x16x32_bf16(Af[k0], Bf[j][k0], acc, 0, 0, 0);
                    #pragma unroll
                    for (int i = 0; i < 4; ++i) {
                        int lrow = m * 16 + g * 4 + i;
                        s_f[lrow * 264 + ch * 128 + n0 * 16 + c] = (short)bf16_rne(fmaxf(acc[i], 0.f));
                    }
                }
            }
        }

        // ================= FF2 + LN2 (row-split; acc held across k-chunks) =================
        f32x4 accA[8], accB[8];
        #pragma unroll
        for (int n0 = 0; n0 < 8; ++n0) {
            float bv = b2[n0 * 16 + c];
            accA[n0] = (f32x4){bv, bv, bv, bv};
            accB[n0] = (f32x4){bv, bv, bv, bv};
        }
        for (int kc = 0; kc < 2; ++kc) {
            __syncthreads();
            {   // stage W2 k-slice
                #pragma unroll
                for (int it = 0; it < 8; ++it) {
                    int cc = it * 256 + tid;
                    int row = cc >> 4, ke = (cc & 15) * 8;
                    uint4 v = *(const uint4*)&W2[row * 256 + kc * 128 + ke];
                    *(uint4*)&s_b[row * 128 + (ke ^ ((row & 7) << 3))] = v;
                }
            }
            __syncthreads();
            // tile A: m = w
            {
                bf16x8 Af[4];
                #pragma unroll
                for (int k0 = 0; k0 < 4; ++k0)
                    Af[k0] = *(const bf16x8*)&s_f[(w * 16 + c) * 264 + kc * 128 + k0 * 32 + kf];
                #pragma unroll
                for (int n0 = 0; n0 < 8; ++n0) {
                    int brow = n0 * 16 + c;
                    #pragma unroll
                    for (int k0 = 0; k0 < 4; ++k0) {
                        bf16x8 bfg = ld_frag(s_b, brow, k0 * 32 + kf, 128);
                        accA[n0] = __builtin_amdgcn_mfma_f32_16x16x32_bf16(Af[k0], bfg, accA[n0], 0, 0, 0);
                    }
                }
            }
            if (w == 0) {   // tile B: m = 4
                bf16x8 Af[4];
                #pragma unroll
                for (int k0 = 0; k0 < 4; ++k0)
                    Af[k0] = *(const bf16x8*)&s_f[(64 + c) * 264 + kc * 128 + k0 * 32 + kf];
                #pragma unroll
                for (int n0 = 0; n0 < 8; ++n0) {
                    int brow = n0 * 16 + c;
                    #pragma unroll
                    for (int k0 = 0; k0 < 4; ++k0) {
                        bf16x8 bfg = ld_frag(s_b, brow, k0 * 32 + kf, 128);
                        accB[n0] = __builtin_amdgcn_mfma_f32_16x16x32_bf16(Af[k0], bfg, accB[n0], 0, 0, 0);
                    }
                }
            }
        }
        // residual (z1 fp32 in s_zf) + LN2 -> new z in s_zf
        {
            #pragma unroll
            for (int n0 = 0; n0 < 8; ++n0)
                #pragma unroll
                for (int i = 0; i < 4; ++i) {
                    int row = w * 16 + g * 4 + i;
                    accA[n0][i] += (row < 72) ? s_zf[row * 132 + n0 * 16 + c] : 0.f;
                }
            float s1[4] = {0,0,0,0}, s2[4] = {0,0,0,0};
            #pragma unroll
            for (int n0 = 0; n0 < 8; ++n0)
                #pragma unroll
                for (int i = 0; i < 4; ++i) { float v = accA[n0][i]; s1[i] += v; s2[i] += v * v; }
            #pragma unroll
            for (int mm = 1; mm < 16; mm <<= 1)
                #pragma unroll
                for (int i = 0; i < 4; ++i) { s1[i] += __shfl_xor(s1[i], mm); s2[i] += __shfl_xor(s2[i], mm); }
            #pragma unroll
            for (int i = 0; i < 4; ++i) {
                float mu = s1[i] * (1.f / D_);
                float var = s2[i] * (1.f / D_) - mu * mu;
                float rstd = rsqrtf(var + 1e-5f);
                int row = w * 16 + g * 4 + i;
                if (row < 72)
                    #pragma unroll
                    for (int n0 = 0; n0 < 8; ++n0)
                        s_zf[row * 132 + n0 * 16 + c] =
                            (accA[n0][i] - mu) * rstd * g2[n0 * 16 + c] + be2[n0 * 16 + c];
            }
        }
        if (w == 0) {
            #pragma unroll
            for (int n0 = 0; n0 < 8; ++n0)
                #pragma unroll
                for (int i = 0; i < 4; ++i) {
                    int row = 64 + g * 4 + i;
                    accB[n0][i] += (row < 72) ? s_zf[row * 132 + n0 * 16 + c] : 0.f;
                }
            float s1[4] = {0,0,0,0}, s2[4] = {0,0,0,0};
            #pragma unroll
            for (int n0 = 0; n0 < 8; ++n0)
                #pragma unroll
                for (int i = 0; i < 4; ++i) { float v = accB[n0][i]; s1[i] += v; s2[i] += v * v; }
            #pragma unroll
            for (int mm = 1; mm < 16; mm <<= 1)
                #pragma unroll
                for (int i = 0; i < 4; ++i) { s1[i] += __shfl_xor(s1[i], mm); s2[i] += __shfl_xor(s2[i], mm); }
            #pragma unroll
            for (int i = 0; i < 4; ++i) {
                float mu = s1[i] * (1.f / D_);
                float var = s2[i] * (1.f / D_) - mu * mu;
                float rstd = rsqrtf(var + 1e-5f);
                int row = 64 + g * 4 + i;
                if (row < 72)
                    #pragma unroll
                    for (int n0 = 0; n0 < 8; ++n0)
                        s_zf[row * 132 + n0 * 16 + c] =
                            (accB[n0][i] - mu) * rstd * g2[n0 * 16 + c] + be2[n0 * 16 + c];
            }
        }
    }

    // ================= HEADS (token 71 only) =================
    __syncthreads();
    float* s_h1 = (float*)s_b;   // [6][64]
    for (int t2 = tid; t2 < 384; t2 += 256) {
        int k = t2 >> 6, j = t2 & 63;
        float acc = hb1[k * 64 + j];
        const float* w1p = hw1 + (size_t)k * D_ * 64 + j;
        for (int d = 0; d < D_; ++d) acc += s_zf[71 * 132 + d] * w1p[d * 64];
        s_h1[k * 64 + j] = fmaxf(acc, 0.f);
    }
    __syncthreads();
    if (tid < 30) {
        int k = tid / 5, s = tid % 5;
        float o = hb2[k * 5 + s];
        const float* w2p = hw2 + (size_t)k * 64 * 5 + s;
        for (int j = 0; j < 64; ++j) o += s_h1[k * 64 + j] * w2p[j * 5];
        out[(size_t)k * (B_ * 5) + b * 5 + s] = o;
    }
}

// ---------------------------------------------------------------------------
extern "C" void kernel_launch(void* const* d_in, const int* in_sizes, int n_in,
                              void* d_out, int out_size, void* d_ws, size_t ws_size,
                              hipStream_t stream) {
    const float* x      = (const float*)d_in[0];
    const int*   ei     = (const int*)  d_in[1];
    const float* gcn_w  = (const float*)d_in[2];
    const float* gcn_b  = (const float*)d_in[3];
    const float* gat_w  = (const float*)d_in[4];
    const float* a_src  = (const float*)d_in[5];
    const float* a_dst  = (const float*)d_in[6];
    const float* gat_b  = (const float*)d_in[7];
    const float* gln_g  = (const float*)d_in[8];
    const float* gln_b  = (const float*)d_in[9];
    const float* tw_qkv = (const float*)d_in[10];
    const float* tb_qkv = (const float*)d_in[11];
    const float* tw_o   = (const float*)d_in[12];
    const float* tb_o   = (const float*)d_in[13];
    const float* ln1_g  = (const float*)d_in[14];
    const float* ln1_b  = (const float*)d_in[15];
    const float* w_ff1  = (const float*)d_in[16];
    const float* b_ff1  = (const float*)d_in[17];
    const float* w_ff2  = (const float*)d_in[18];
    const float* b_ff2  = (const float*)d_in[19];
    const float* ln2_g  = (const float*)d_in[20];
    const float* ln2_b  = (const float*)d_in[21];
    const float* hw1    = (const float*)d_in[22];
    const float* hb1    = (const float*)d_in[23];
    const float* hw2    = (const float*)d_in[24];
    const float* hb2    = (const float*)d_in[25];
    float* out = (float*)d_out;
    float* ws  = (float*)d_ws;

    float* z   = ws + WS_Z;
    short* wbf = (short*)(ws + WS_WBF);

    short* hbuf = (short*)(ws + WS_QKV);       // graph scratch aliases qkv region
    float* asb  = ws + WS_OBUF;
    float* adb  = ws + WS_OBUF + BT_ * 5 * 4;

    const int E = in_sizes[1] / 2;   // 20
    const int E2 = E + N_;           // 25

    // allow >64KB dynamic LDS for the mega kernel (idempotent, capture-safe)
    static bool attr_set = false;
    if (!attr_set) {
        hipFuncSetAttribute((const void*)layers_fused,
                            hipFuncAttributeMaxDynamicSharedMemorySize, MSMEM_BYTES);
        attr_set = true;
    }

    setup_kernel<<<1, 64, 0, stream>>>(ei, ws, E);
    prep_kernel<<<98, 256, 0, stream>>>(tw_qkv, tw_o, w_ff1, w_ff2, gat_w, wbf);
    gcn_h_mfma<<<BT_ / 16, 256, 0, stream>>>(x, gcn_w, gcn_b, a_src, a_dst, ws,
                                             wbf + WOFF_GATW, hbuf, asb, adb);
    gat_agg<<<BT_ / 4, 256, 0, stream>>>(hbuf, asb, adb, gat_b, gln_g, gln_b, ws, z, E2);
    layers_fused<<<B_, 256, MSMEM_BYTES, stream>>>(z, wbf, tb_qkv, tb_o,
                                                   ln1_g, ln1_b, b_ff1, b_ff2,
                                                   ln2_g, ln2_b, hw1, hb1, hw2, hb2, out);
}

// Round 9
// 289.653 us; speedup vs baseline: 1.2277x; 1.2277x over previous
//
#include <hip/hip_runtime.h>
#include <hip/hip_bf16.h>

// Problem constants (fixed by the reference)
#define B_  256
#define T_  72
#define N_  5
#define F_  10
#define D_  128
#define HH_ 4
#define CC_ 32
#define FF_ 256
#define BT_ (B_*T_)   // 18432
#define E2MAX 32

// ---------------- ws layout (float offsets) ----------------
#define WS_Z    256
#define WS_QKV  (WS_Z + BT_*D_)
#define WS_OBUF (WS_QKV + BT_*3*D_)
#define WS_WBF  (WS_OBUF + BT_*D_)      // bf16 weight region

// bf16 weight offsets (in shorts, from WS_WBF base)
#define WOFF_QKV(i)  ((i)*49152)                 // [384][128]
#define WOFF_O(i)    (147456 + (i)*16384)        // [128][128]
#define WOFF_FF1(i)  (196608 + (i)*32768)        // [256][128]
#define WOFF_FF2(i)  (294912 + (i)*32768)        // [128][256]
#define WOFF_GATW    393216                      // [128][64]

// ---------------- mega-kernel LDS carve (bytes) ----------------
#define MZF_OFF   0          // float [72][132]           38,016
#define MSB_OFF   38016      // short [128][128] (weights; P strips & h1 alias) 32,768
#define MSQ_OFF   70784      // short [80][136]           21,760  (s_f part 1)
#define MSK_OFF   92544      // short [80][136]           21,760  (s_f part 2)
#define MVT_OFF   114304     // short [128][104]          26,624  (z1 bf16 aliases)
#define MOB_OFF   140928     // short [80][136]           21,760
#define MSMEM_BYTES 162688

typedef __attribute__((ext_vector_type(8))) short bf16x8;
typedef __attribute__((ext_vector_type(4))) float f32x4;

__device__ __forceinline__ unsigned short bf16_rne(float x) {
    unsigned u = __float_as_uint(x);
    unsigned r = (u + 0x7FFFu + ((u >> 16) & 1u)) >> 16;
    return (unsigned short)r;
}
__device__ __forceinline__ unsigned bf16pk(float a, float b) {
    return (unsigned)bf16_rne(a) | ((unsigned)bf16_rne(b) << 16);
}
__device__ __forceinline__ float bf2f(short s) {
    return __uint_as_float(((unsigned)(unsigned short)s) << 16);
}
// convert 8 consecutive fp32 (16B-aligned) to bf16x8
__device__ __forceinline__ bf16x8 cvt8(const float* p) {
    float4 a = *(const float4*)p;
    float4 b = *(const float4*)(p + 4);
    unsigned u[4] = {bf16pk(a.x, a.y), bf16pk(a.z, a.w), bf16pk(b.x, b.y), bf16pk(b.z, b.w)};
    return *(bf16x8*)u;
}

// ---------------------------------------------------------------------------
__global__ void setup_kernel(const int* __restrict__ ei, float* __restrict__ ws, int E) {
    if (threadIdx.x != 0 || blockIdx.x != 0) return;
    int* wsi = (int*)ws;
    const int N = N_;
    int E2 = E + N;
    int src2[E2MAX], dst2[E2MAX];
    for (int e = 0; e < E; ++e) { src2[e] = ei[e]; dst2[e] = ei[E + e]; }
    for (int n = 0; n < N; ++n) { src2[E + n] = n; dst2[E + n] = n; }
    float A[N_ * N_];
    for (int i = 0; i < N * N; ++i) A[i] = 0.f;
    for (int e = 0; e < E2; ++e) A[dst2[e] * N + src2[e]] += 1.f;
    float dinv[N_];
    for (int n = 0; n < N; ++n) {
        float s = 0.f;
        for (int j = 0; j < N; ++j) s += A[n * N + j];
        dinv[n] = (s > 0.f) ? rsqrtf(s) : 0.f;
    }
    for (int n = 0; n < N; ++n)
        for (int j = 0; j < N; ++j)
            ws[n * N + j] = dinv[n] * A[n * N + j] * dinv[j];
    int cnt[N_];
    for (int n = 0; n < N; ++n) cnt[n] = 0;
    for (int e = 0; e < E2; ++e) cnt[dst2[e]]++;
    int off = 0;
    for (int n = 0; n < N; ++n) { wsi[96 + n] = off; off += cnt[n]; }
    wsi[96 + N] = off;
    int cur[N_];
    for (int n = 0; n < N; ++n) cur[n] = wsi[96 + n];
    for (int e = 0; e < E2; ++e) wsi[104 + cur[dst2[e]]++] = e;
    for (int e = 0; e < E2; ++e) { wsi[32 + e] = src2[e]; wsi[64 + e] = dst2[e]; }
}

// ---------------------------------------------------------------------------
// Weight prep: transpose R x C fp32 -> [C][R] bf16 into ws.
__global__ __launch_bounds__(256) void prep_kernel(
    const float* __restrict__ tw_qkv, const float* __restrict__ tw_o,
    const float* __restrict__ w_ff1, const float* __restrict__ w_ff2,
    const float* __restrict__ gat_w, short* __restrict__ wbf)
{
    __shared__ float s_t[64][65];
    const int tid = threadIdx.x;
    int t = blockIdx.x;
    const float* src; short* dst; int R, C, tr, tc;
    if (t >= 96) { int q = t - 96; src = gat_w; dst = wbf + WOFF_GATW; R = 64; C = 128; tr = 0; tc = q; }
    else {
        int layer = t / 32, r32 = t % 32;
        if (r32 < 12)      { src = tw_qkv + layer * (128*384); dst = wbf + WOFF_QKV(layer); R = 128; C = 384; tr = r32 / 6;  tc = r32 % 6; }
        else if (r32 < 16) { int q = r32 - 12; src = tw_o + layer * 16384; dst = wbf + WOFF_O(layer);  R = 128; C = 128; tr = q >> 1; tc = q & 1; }
        else if (r32 < 24) { int q = r32 - 16; src = w_ff1 + layer * 32768; dst = wbf + WOFF_FF1(layer); R = 128; C = 256; tr = q >> 2; tc = q & 3; }
        else               { int q = r32 - 24; src = w_ff2 + layer * 32768; dst = wbf + WOFF_FF2(layer); R = 256; C = 128; tr = q >> 1; tc = q & 1; }
    }
    #pragma unroll
    for (int it = 0; it < 16; ++it) {
        int e = it * 256 + tid;
        int r = e >> 6, c = e & 63;
        s_t[r][c] = src[(size_t)(tr*64 + r) * C + tc*64 + c];
    }
    __syncthreads();
    #pragma unroll
    for (int it = 0; it < 16; ++it) {
        int e = it * 256 + tid;
        int c = e >> 6, r = e & 63;
        dst[(size_t)(tc*64 + c) * R + tr*64 + r] = (short)bf16_rne(s_t[r][c]);
    }
}

// ---------------------------------------------------------------------------
// MFMA helpers: swizzled LDS B tiles
__device__ __forceinline__ bf16x8 ld_frag(const short* s, int row, int kbase, int ldk) {
    return *(const bf16x8*)&s[row * ldk + (kbase ^ ((row & 7) << 3))];
}
__device__ __forceinline__ void stage_b(short* s_b, const short* __restrict__ src, int tid) {
    const uint4* s4 = (const uint4*)src;
    #pragma unroll
    for (int it = 0; it < 8; ++it) {
        int c = it * 256 + tid;
        int row = c >> 4, ke = (c & 15) * 8;
        *(uint4*)&s_b[row * 128 + (ke ^ ((row & 7) << 3))] = s4[c];
    }
}
// 512-thread variant
__device__ __forceinline__ void stage_b512(short* s_b, const short* __restrict__ src, int tid) {
    const uint4* s4 = (const uint4*)src;
    #pragma unroll
    for (int it = 0; it < 4; ++it) {
        int c = it * 512 + tid;
        int row = c >> 4, ke = (c & 15) * 8;
        *(uint4*)&s_b[row * 128 + (ke ^ ((row & 7) << 3))] = s4[c];
    }
}

// ---------------------------------------------------------------------------
// G1: x -> GCN(tanh) -> h = gcn @ gat_w (MFMA) -> h (bf16 global), a_s/a_d (global)
__global__ __launch_bounds__(256) void gcn_h_mfma(
    const float* __restrict__ x, const float* __restrict__ gcn_w, const float* __restrict__ gcn_b,
    const float* __restrict__ a_src, const float* __restrict__ a_dst,
    const float* __restrict__ ws, const short* __restrict__ gwT,
    short* __restrict__ hbuf, float* __restrict__ asb, float* __restrict__ adb)
{
    __shared__ float s_x[16 * 50];
    __shared__ float s_an[25];
    __shared__ short s_gcn[80 * 64];

    const int tid = threadIdx.x;
    const int tok0 = blockIdx.x * 16;

    for (int i = tid; i < 16 * 50; i += 256) s_x[i] = x[(size_t)tok0 * 50 + i];
    if (tid < 25) s_an[tid] = ws[tid];
    __syncthreads();

    #pragma unroll
    for (int it = 0; it < 2; ++it) {
        int idx = it * 256 + tid;
        int tl = idx >> 5, kp = idx & 31;
        int k0 = kp * 2;
        float w0[F_], w1[F_];
        #pragma unroll
        for (int f = 0; f < F_; ++f) { w0[f] = gcn_w[f * 64 + k0]; w1[f] = gcn_w[f * 64 + k0 + 1]; }
        float b0 = gcn_b[k0], b1 = gcn_b[k0 + 1];
        float xw0[N_], xw1[N_];
        #pragma unroll
        for (int n = 0; n < N_; ++n) {
            float a0 = b0, a1 = b1;
            #pragma unroll
            for (int f = 0; f < F_; ++f) {
                float xv = s_x[tl * 50 + n * 10 + f];
                a0 += xv * w0[f]; a1 += xv * w1[f];
            }
            xw0[n] = a0; xw1[n] = a1;
        }
        #pragma unroll
        for (int n = 0; n < N_; ++n) {
            float s0 = 0.f, s1 = 0.f;
            #pragma unroll
            for (int j = 0; j < N_; ++j) { float an = s_an[n * 5 + j]; s0 += an * xw0[j]; s1 += an * xw1[j]; }
            float e0 = __expf(2.f * fabsf(s0)), e1 = __expf(2.f * fabsf(s1));
            float t0 = copysignf(1.f - 2.f / (e0 + 1.f), s0);
            float t1 = copysignf(1.f - 2.f / (e1 + 1.f), s1);
            int row = tl * 5 + n;
            *(unsigned*)&s_gcn[row * 64 + (k0 ^ ((row & 7) << 3))] = bf16pk(t0, t1);
        }
    }
    __syncthreads();

    const int w = tid >> 6, lane = tid & 63;
    const int c = lane & 15, g = lane >> 4;
    const int kf = g * 8;
    bf16x8 bfr[2][2];
    #pragma unroll
    for (int nn = 0; nn < 2; ++nn)
        #pragma unroll
        for (int k0 = 0; k0 < 2; ++k0)
            bfr[nn][k0] = *(const bf16x8*)&gwT[(w * 32 + nn * 16 + c) * 64 + k0 * 32 + kf];
    const float as0 = a_src[w * 32 + c],      as1 = a_src[w * 32 + 16 + c];
    const float ad0 = a_dst[w * 32 + c],      ad1 = a_dst[w * 32 + 16 + c];
    #pragma unroll
    for (int m = 0; m < 5; ++m) {
        bf16x8 af0 = ld_frag(s_gcn, m * 16 + c, kf, 64);
        bf16x8 af1 = ld_frag(s_gcn, m * 16 + c, 32 + kf, 64);
        f32x4 a0 = {0,0,0,0}, a1 = {0,0,0,0};
        a0 = __builtin_amdgcn_mfma_f32_16x16x32_bf16(af0, bfr[0][0], a0, 0, 0, 0);
        a0 = __builtin_amdgcn_mfma_f32_16x16x32_bf16(af1, bfr[0][1], a0, 0, 0, 0);
        a1 = __builtin_amdgcn_mfma_f32_16x16x32_bf16(af0, bfr[1][0], a1, 0, 0, 0);
        a1 = __builtin_amdgcn_mfma_f32_16x16x32_bf16(af1, bfr[1][1], a1, 0, 0, 0);
        float ps[4], pd[4];
        #pragma unroll
        for (int i = 0; i < 4; ++i) {
            int row = m * 16 + g * 4 + i;
            size_t gr = (size_t)(tok0 * 5 + row) * 128;
            hbuf[gr + w * 32 + c]      = (short)bf16_rne(a0[i]);
            hbuf[gr + w * 32 + 16 + c] = (short)bf16_rne(a1[i]);
            ps[i] = a0[i] * as0 + a1[i] * as1;
            pd[i] = a0[i] * ad0 + a1[i] * ad1;
        }
        #pragma unroll
        for (int mm = 1; mm < 16; mm <<= 1)
            #pragma unroll
            for (int i = 0; i < 4; ++i) { ps[i] += __shfl_xor(ps[i], mm); pd[i] += __shfl_xor(pd[i], mm); }
        if (c == 0) {
            #pragma unroll
            for (int i = 0; i < 4; ++i) {
                int row = m * 16 + g * 4 + i;
                asb[(size_t)(tok0 * 5 + row) * 4 + w] = ps[i];
                adb[(size_t)(tok0 * 5 + row) * 4 + w] = pd[i];
            }
        }
    }
}

// ---------------------------------------------------------------------------
// G2: alpha softmax + aggregate + gat_b + LN + mean + PE -> z
__global__ __launch_bounds__(256) void gat_agg(
    const short* __restrict__ hbuf, const float* __restrict__ asb, const float* __restrict__ adb,
    const float* __restrict__ gat_b, const float* __restrict__ gln_g, const float* __restrict__ gln_b,
    const float* __restrict__ ws, float* __restrict__ z, int E2)
{
    __shared__ int   s_src[E2MAX], s_csr_off[N_ + 1], s_csr_e[E2MAX];
    __shared__ float s_alpha[4][E2MAX][4];
    __shared__ short s_h[4 * 5 * 128];

    const int tid = threadIdx.x;
    const int wv = tid >> 6, lane = tid & 63;
    const int tok = blockIdx.x * 4 + wv;
    const int* wsi = (const int*)ws;

    if (tid < E2) { s_src[tid] = wsi[32 + tid]; s_csr_e[tid] = wsi[104 + tid]; }
    if (tid < N_ + 1) s_csr_off[tid] = wsi[96 + tid];
    {
        const uint4* hb4 = (const uint4*)(hbuf + (size_t)blockIdx.x * 4 * 5 * 128);
        uint4* sh4 = (uint4*)s_h;
        #pragma unroll
        for (int it = 0; it < 2; ++it) {
            int i = it * 256 + tid;
            if (i < 320) sh4[i] = hb4[i];
        }
    }
    __syncthreads();

    if (lane < 20) {
        int dn = lane >> 2, head = lane & 3;
        int j0 = s_csr_off[dn], j1 = s_csr_off[dn + 1];
        float adv = adb[(size_t)(tok * 5 + dn) * 4 + head];
        float mx = -1e30f;
        for (int j = j0; j < j1; ++j) {
            int e = s_csr_e[j];
            float ev = asb[(size_t)(tok * 5 + s_src[e]) * 4 + head] + adv;
            ev = ev > 0.f ? ev : 0.2f * ev;
            mx = fmaxf(mx, ev);
        }
        float den = 0.f;
        for (int j = j0; j < j1; ++j) {
            int e = s_csr_e[j];
            float ev = asb[(size_t)(tok * 5 + s_src[e]) * 4 + head] + adv;
            ev = ev > 0.f ? ev : 0.2f * ev;
            float ex = __expf(ev - mx);
            den += ex;
            s_alpha[wv][e][head] = ex;
        }
        float r = 1.f / den;
        for (int j = j0; j < j1; ++j) s_alpha[wv][s_csr_e[j]][head] *= r;
    }
    __syncthreads();

    const int h0 = lane >> 5, h1 = 2 + (lane >> 5);
    const float gb0 = gat_b[lane],      gb1 = gat_b[lane + 64];
    const float gg0 = gln_g[lane],      gg1 = gln_g[lane + 64];
    const float gB0 = gln_b[lane],      gB1 = gln_b[lane + 64];
    float v0[N_], v1[N_];
    #pragma unroll
    for (int n = 0; n < N_; ++n) {
        float a0 = 0.f, a1 = 0.f;
        int j0 = s_csr_off[n], j1 = s_csr_off[n + 1];
        for (int j = j0; j < j1; ++j) {
            int e = s_csr_e[j];
            int rb = (wv * 5 + s_src[e]) * 128;
            a0 += s_alpha[wv][e][h0] * bf2f(s_h[rb + lane]);
            a1 += s_alpha[wv][e][h1] * bf2f(s_h[rb + lane + 64]);
        }
        v0[n] = a0 + gb0; v1[n] = a1 + gb1;
    }
    float r1[N_], r2[N_];
    #pragma unroll
    for (int n = 0; n < N_; ++n) { r1[n] = v0[n] + v1[n]; r2[n] = v0[n]*v0[n] + v1[n]*v1[n]; }
    #pragma unroll
    for (int mm = 1; mm < 64; mm <<= 1)
        #pragma unroll
        for (int n = 0; n < N_; ++n) { r1[n] += __shfl_xor(r1[n], mm); r2[n] += __shfl_xor(r2[n], mm); }
    float z0 = 0.f, z1 = 0.f;
    #pragma unroll
    for (int n = 0; n < N_; ++n) {
        float mu = r1[n] * (1.f / D_);
        float var = r2[n] * (1.f / D_) - mu * mu;
        float rstd = rsqrtf(var + 1e-5f);
        z0 += (v0[n] - mu) * rstd * gg0 + gB0;
        z1 += (v1[n] - mu) * rstd * gg1 + gB1;
    }
    z0 *= (1.f / N_); z1 *= (1.f / N_);
    const float cpe = -9.210340371976184f / (float)D_;
    int t = tok % T_;
    float dv0 = __expf((float)(lane & ~1) * cpe);
    float dv1 = __expf((float)((lane + 64) & ~1) * cpe);
    float ang0 = (float)t * dv0, ang1 = (float)t * dv1;
    z0 += (lane & 1) ? __cosf(ang0) : __sinf(ang0);
    z1 += (lane & 1) ? __cosf(ang1) : __sinf(ang1);
    z[(size_t)tok * D_ + lane] = z0;
    z[(size_t)tok * D_ + 64 + lane] = z1;
}

// ---------------------------------------------------------------------------
// MEGA: all 3 transformer layers + 6 heads, one block per batch (grid 256).
// 512 threads = 8 waves = 2 waves/SIMD for latency hiding.
__global__ __launch_bounds__(512, 1) void layers_fused(
    const float* __restrict__ zg, const short* __restrict__ wbf,
    const float* __restrict__ tb_qkv, const float* __restrict__ tb_o,
    const float* __restrict__ ln1_g, const float* __restrict__ ln1_b,
    const float* __restrict__ b_ff1, const float* __restrict__ b_ff2,
    const float* __restrict__ ln2_g, const float* __restrict__ ln2_b,
    const float* __restrict__ hw1, const float* __restrict__ hb1,
    const float* __restrict__ hw2, const float* __restrict__ hb2,
    float* __restrict__ out)
{
    extern __shared__ char smem[];
    float* s_zf = (float*)(smem + MZF_OFF);          // [72][132]
    short* s_b  = (short*)(smem + MSB_OFF);          // [128][128] swizzled weights
    short* s_q  = (short*)(smem + MSQ_OFF);          // [80][136]
    short* s_k  = (short*)(smem + MSK_OFF);          // [80][136]
    short* s_vt = (short*)(smem + MVT_OFF);          // [128][104]; z1 bf16 aliases
    short* s_ob = (short*)(smem + MOB_OFF);          // [80][136]
    short* s_f  = s_q;                               // [80][264] (q+k region)
    short* s_z1 = s_vt;                              // [80][136]

    const int tid = threadIdx.x;
    const int w = tid >> 6, lane = tid & 63;         // w = 0..7
    const int c = lane & 15, g = lane >> 4;
    const int kf = g * 8;
    const int b = blockIdx.x;

    // ---- load z (fp32) -> s_zf; zero s_vt tail keys once
    for (int idx = tid; idx < 72 * 128; idx += 512) {
        int r = idx >> 7, col = idx & 127;
        s_zf[r * 132 + col] = zg[(size_t)(b * T_ + r) * D_ + col];
    }
    for (int idx = tid; idx < 128 * 32; idx += 512) {
        int ch = idx >> 5, key = 72 + (idx & 31);
        s_vt[ch * 104 + key] = 0;
    }
    __syncthreads();

    for (int L = 0; L < 3; ++L) {
        const short* Wq = wbf + WOFF_QKV(L);
        const short* Wo = wbf + WOFF_O(L);
        const short* W1 = wbf + WOFF_FF1(L);
        const short* W2 = wbf + WOFF_FF2(L);
        const float* bq = tb_qkv + L * 384;
        const float* bo = tb_o + L * D_;
        const float* g1 = ln1_g + L * D_, *be1 = ln1_b + L * D_;
        const float* b1 = b_ff1 + L * FF_, *b2 = b_ff2 + L * D_;
        const float* g2 = ln2_g + L * D_, *be2 = ln2_b + L * D_;

        // ================= QKV: 3 chunks of 128 cols; wave owns n0 = w =================
        for (int ch = 0; ch < 3; ++ch) {
            __syncthreads();
            stage_b512(s_b, Wq + ch * 16384, tid);
            __syncthreads();
            const int n0 = w;
            const int brow = n0 * 16 + c;
            bf16x8 Bf[4];
            #pragma unroll
            for (int k0 = 0; k0 < 4; ++k0) Bf[k0] = ld_frag(s_b, brow, k0 * 32 + kf, 128);
            const float bv = bq[ch * 128 + n0 * 16 + c];
            const int wcol = n0 * 16 + c;
            #pragma unroll
            for (int m = 0; m < 5; ++m) {
                int arow = m * 16 + c;
                bool valid = arow < 72;
                bf16x8 Af[4];
                bf16x8 z8 = {0,0,0,0,0,0,0,0};
                #pragma unroll
                for (int k0 = 0; k0 < 4; ++k0)
                    Af[k0] = valid ? cvt8(&s_zf[arow * 132 + k0 * 32 + kf]) : z8;
                f32x4 acc = {bv, bv, bv, bv};
                #pragma unroll
                for (int k0 = 0; k0 < 4; ++k0)
                    acc = __builtin_amdgcn_mfma_f32_16x16x32_bf16(Af[k0], Bf[k0], acc, 0, 0, 0);
                #pragma unroll
                for (int i = 0; i < 4; ++i) {
                    int lrow = m * 16 + g * 4 + i;
                    short v = (short)bf16_rne(acc[i]);
                    if (ch == 0)      s_q[lrow * 136 + wcol] = v;
                    else if (ch == 1) s_k[lrow * 136 + wcol] = v;
                    else              s_vt[wcol * 104 + lrow] = v;
                }
            }
        }
        __syncthreads();   // q,k,vt visible

        // ================= ATTENTION: wave w -> head w&3, m-range by w>>2 =================
        {
            short* pstrip = s_b + w * (16 * 104);   // 8 strips = 26,624 B <= 32,768 B
            for (int t2 = lane; t2 < 16 * 24; t2 += 64) {
                int r = t2 / 24, col = 80 + (t2 % 24);
                pstrip[r * 104 + col] = 0;
            }
            const int h = w & 3;
            const int mlo = (w >> 2) ? 3 : 0;
            const int mhi = (w >> 2) ? 5 : 3;
            const float scale = 0.17677669529663687f;
            for (int m = mlo; m < mhi; ++m) {
                bf16x8 aq = *(const bf16x8*)&s_q[(m * 16 + c) * 136 + h * 32 + kf];
                float ps[5][4], mx[4], den[4];
                #pragma unroll
                for (int i = 0; i < 4; ++i) mx[i] = -1e30f;
                #pragma unroll
                for (int n0 = 0; n0 < 5; ++n0) {
                    bf16x8 bk = *(const bf16x8*)&s_k[(n0 * 16 + c) * 136 + h * 32 + kf];
                    f32x4 z4 = {0,0,0,0};
                    f32x4 accS = __builtin_amdgcn_mfma_f32_16x16x32_bf16(aq, bk, z4, 0, 0, 0);
                    #pragma unroll
                    for (int i = 0; i < 4; ++i) {
                        float s = accS[i] * scale;
                        if (n0 == 4 && c >= 8) s = -1e30f;
                        ps[n0][i] = s;
                        mx[i] = fmaxf(mx[i], s);
                    }
                }
                #pragma unroll
                for (int mm = 1; mm < 16; mm <<= 1)
                    #pragma unroll
                    for (int i = 0; i < 4; ++i) mx[i] = fmaxf(mx[i], __shfl_xor(mx[i], mm));
                #pragma unroll
                for (int i = 0; i < 4; ++i) den[i] = 0.f;
                #pragma unroll
                for (int n0 = 0; n0 < 5; ++n0)
                    #pragma unroll
                    for (int i = 0; i < 4; ++i) { float e = __expf(ps[n0][i] - mx[i]); ps[n0][i] = e; den[i] += e; }
                #pragma unroll
                for (int mm = 1; mm < 16; mm <<= 1)
                    #pragma unroll
                    for (int i = 0; i < 4; ++i) den[i] += __shfl_xor(den[i], mm);
                float rden[4];
                #pragma unroll
                for (int i = 0; i < 4; ++i) rden[i] = 1.f / den[i];
                #pragma unroll
                for (int n0 = 0; n0 < 5; ++n0)
                    #pragma unroll
                    for (int i = 0; i < 4; ++i)
                        pstrip[(g * 4 + i) * 104 + n0 * 16 + c] = (short)bf16_rne(ps[n0][i] * rden[i]);
                // PV (wave-private P strip)
                f32x4 accO[2] = {{0,0,0,0},{0,0,0,0}};
                #pragma unroll
                for (int kt = 0; kt < 3; ++kt) {
                    bf16x8 ap = *(const bf16x8*)&pstrip[c * 104 + kt * 32 + kf];
                    #pragma unroll
                    for (int n0 = 0; n0 < 2; ++n0) {
                        bf16x8 bv = *(const bf16x8*)&s_vt[(h * 32 + n0 * 16 + c) * 104 + kt * 32 + kf];
                        accO[n0] = __builtin_amdgcn_mfma_f32_16x16x32_bf16(ap, bv, accO[n0], 0, 0, 0);
                    }
                }
                #pragma unroll
                for (int n0 = 0; n0 < 2; ++n0)
                    #pragma unroll
                    for (int i = 0; i < 4; ++i)
                        s_ob[(m * 16 + g * 4 + i) * 136 + h * 32 + n0 * 16 + c] = (short)bf16_rne(accO[n0][i]);
            }
        }
        __syncthreads();   // s_ob visible; P strips dead

        // ================= O-PROJ + LN1 (waves 0..4 own m = w) =================
        stage_b512(s_b, Wo, tid);
        __syncthreads();
        if (w < 5) {
            const int m = w;
            bf16x8 Af[4];
            #pragma unroll
            for (int k0 = 0; k0 < 4; ++k0)
                Af[k0] = *(const bf16x8*)&s_ob[(m * 16 + c) * 136 + k0 * 32 + kf];
            f32x4 acc[8];
            #pragma unroll
            for (int n0 = 0; n0 < 8; ++n0) {
                float bv = bo[n0 * 16 + c];
                acc[n0] = (f32x4){bv, bv, bv, bv};
                int brow = n0 * 16 + c;
                #pragma unroll
                for (int k0 = 0; k0 < 4; ++k0) {
                    bf16x8 bfg = ld_frag(s_b, brow, k0 * 32 + kf, 128);
                    acc[n0] = __builtin_amdgcn_mfma_f32_16x16x32_bf16(Af[k0], bfg, acc[n0], 0, 0, 0);
                }
            }
            #pragma unroll
            for (int n0 = 0; n0 < 8; ++n0)
                #pragma unroll
                for (int i = 0; i < 4; ++i) {
                    int row = m * 16 + g * 4 + i;
                    acc[n0][i] += (row < 72) ? s_zf[row * 132 + n0 * 16 + c] : 0.f;
                }
            float s1[4] = {0,0,0,0}, s2[4] = {0,0,0,0};
            #pragma unroll
            for (int n0 = 0; n0 < 8; ++n0)
                #pragma unroll
                for (int i = 0; i < 4; ++i) { float v = acc[n0][i]; s1[i] += v; s2[i] += v * v; }
            #pragma unroll
            for (int mm = 1; mm < 16; mm <<= 1)
                #pragma unroll
                for (int i = 0; i < 4; ++i) { s1[i] += __shfl_xor(s1[i], mm); s2[i] += __shfl_xor(s2[i], mm); }
            #pragma unroll
            for (int i = 0; i < 4; ++i) {
                float mu = s1[i] * (1.f / D_);
                float var = s2[i] * (1.f / D_) - mu * mu;
                float rstd = rsqrtf(var + 1e-5f);
                int row = m * 16 + g * 4 + i;
                #pragma unroll
                for (int n0 = 0; n0 < 8; ++n0) {
                    float v = (acc[n0][i] - mu) * rstd * g1[n0 * 16 + c] + be1[n0 * 16 + c];
                    if (row < 72) s_zf[row * 132 + n0 * 16 + c] = v;
                    s_z1[row * 136 + n0 * 16 + c] = (short)bf16_rne(v);
                }
            }
        }

        // ================= FF1 (wave owns n0 = w per chunk) =================
        for (int ch = 0; ch < 2; ++ch) {
            __syncthreads();
            stage_b512(s_b, W1 + ch * 16384, tid);
            __syncthreads();
            const int n0 = w;
            const int brow = n0 * 16 + c;
            bf16x8 Bf[4];
            #pragma unroll
            for (int k0 = 0; k0 < 4; ++k0) Bf[k0] = ld_frag(s_b, brow, k0 * 32 + kf, 128);
            const float bv = b1[ch * 128 + n0 * 16 + c];
            #pragma unroll
            for (int m = 0; m < 5; ++m) {
                bf16x8 Af[4];
                #pragma unroll
                for (int k0 = 0; k0 < 4; ++k0)
                    Af[k0] = *(const bf16x8*)&s_z1[(m * 16 + c) * 136 + k0 * 32 + kf];
                f32x4 acc = {bv, bv, bv, bv};
                #pragma unroll
                for (int k0 = 0; k0 < 4; ++k0)
                    acc = __builtin_amdgcn_mfma_f32_16x16x32_bf16(Af[k0], Bf[k0], acc, 0, 0, 0);
                #pragma unroll
                for (int i = 0; i < 4; ++i) {
                    int lrow = m * 16 + g * 4 + i;
                    s_f[lrow * 264 + ch * 128 + n0 * 16 + c] = (short)bf16_rne(fmaxf(acc[i], 0.f));
                }
            }
        }

        // ================= FF2 + LN2 (waves 0..4 own m = w; acc across k-chunks) =================
        f32x4 acc2[8];
        #pragma unroll
        for (int n0 = 0; n0 < 8; ++n0) {
            float bv = b2[n0 * 16 + c];
            acc2[n0] = (f32x4){bv, bv, bv, bv};
        }
        for (int kc = 0; kc < 2; ++kc) {
            __syncthreads();
            {   // stage W2 k-slice (512 threads)
                #pragma unroll
                for (int it = 0; it < 4; ++it) {
                    int cc = it * 512 + tid;
                    int row = cc >> 4, ke = (cc & 15) * 8;
                    uint4 v = *(const uint4*)&W2[row * 256 + kc * 128 + ke];
                    *(uint4*)&s_b[row * 128 + (ke ^ ((row & 7) << 3))] = v;
                }
            }
            __syncthreads();
            if (w < 5) {
                bf16x8 Af[4];
                #pragma unroll
                for (int k0 = 0; k0 < 4; ++k0)
                    Af[k0] = *(const bf16x8*)&s_f[(w * 16 + c) * 264 + kc * 128 + k0 * 32 + kf];
                #pragma unroll
                for (int n0 = 0; n0 < 8; ++n0) {
                    int brow = n0 * 16 + c;
                    #pragma unroll
                    for (int k0 = 0; k0 < 4; ++k0) {
                        bf16x8 bfg = ld_frag(s_b, brow, k0 * 32 + kf, 128);
                        acc2[n0] = __builtin_amdgcn_mfma_f32_16x16x32_bf16(Af[k0], bfg, acc2[n0], 0, 0, 0);
                    }
                }
            }
        }
        if (w < 5) {
            const int m = w;
            #pragma unroll
            for (int n0 = 0; n0 < 8; ++n0)
                #pragma unroll
                for (int i = 0; i < 4; ++i) {
                    int row = m * 16 + g * 4 + i;
                    acc2[n0][i] += (row < 72) ? s_zf[row * 132 + n0 * 16 + c] : 0.f;
                }
            float s1[4] = {0,0,0,0}, s2[4] = {0,0,0,0};
            #pragma unroll
            for (int n0 = 0; n0 < 8; ++n0)
                #pragma unroll
                for (int i = 0; i < 4; ++i) { float v = acc2[n0][i]; s1[i] += v; s2[i] += v * v; }
            #pragma unroll
            for (int mm = 1; mm < 16; mm <<= 1)
                #pragma unroll
                for (int i = 0; i < 4; ++i) { s1[i] += __shfl_xor(s1[i], mm); s2[i] += __shfl_xor(s2[i], mm); }
            #pragma unroll
            for (int i = 0; i < 4; ++i) {
                float mu = s1[i] * (1.f / D_);
                float var = s2[i] * (1.f / D_) - mu * mu;
                float rstd = rsqrtf(var + 1e-5f);
                int row = m * 16 + g * 4 + i;
                if (row < 72)
                    #pragma unroll
                    for (int n0 = 0; n0 < 8; ++n0)
                        s_zf[row * 132 + n0 * 16 + c] =
                            (acc2[n0][i] - mu) * rstd * g2[n0 * 16 + c] + be2[n0 * 16 + c];
            }
        }
    }

    // ================= HEADS (token 71 only) =================
    __syncthreads();
    float* s_h1 = (float*)s_b;   // [6][64]
    for (int t2 = tid; t2 < 384; t2 += 512) {
        int k = t2 >> 6, j = t2 & 63;
        float acc = hb1[k * 64 + j];
        const float* w1p = hw1 + (size_t)k * D_ * 64 + j;
        for (int d = 0; d < D_; ++d) acc += s_zf[71 * 132 + d] * w1p[d * 64];
        s_h1[k * 64 + j] = fmaxf(acc, 0.f);
    }
    __syncthreads();
    if (tid < 30) {
        int k = tid / 5, s = tid % 5;
        float o = hb2[k * 5 + s];
        const float* w2p = hw2 + (size_t)k * 64 * 5 + s;
        for (int j = 0; j < 64; ++j) o += s_h1[k * 64 + j] * w2p[j * 5];
        out[(size_t)k * (B_ * 5) + b * 5 + s] = o;
    }
}

// ---------------------------------------------------------------------------
extern "C" void kernel_launch(void* const* d_in, const int* in_sizes, int n_in,
                              void* d_out, int out_size, void* d_ws, size_t ws_size,
                              hipStream_t stream) {
    const float* x      = (const float*)d_in[0];
    const int*   ei     = (const int*)  d_in[1];
    const float* gcn_w  = (const float*)d_in[2];
    const float* gcn_b  = (const float*)d_in[3];
    const float* gat_w  = (const float*)d_in[4];
    const float* a_src  = (const float*)d_in[5];
    const float* a_dst  = (const float*)d_in[6];
    const float* gat_b  = (const float*)d_in[7];
    const float* gln_g  = (const float*)d_in[8];
    const float* gln_b  = (const float*)d_in[9];
    const float* tw_qkv = (const float*)d_in[10];
    const float* tb_qkv = (const float*)d_in[11];
    const float* tw_o   = (const float*)d_in[12];
    const float* tb_o   = (const float*)d_in[13];
    const float* ln1_g  = (const float*)d_in[14];
    const float* ln1_b  = (const float*)d_in[15];
    const float* w_ff1  = (const float*)d_in[16];
    const float* b_ff1  = (const float*)d_in[17];
    const float* w_ff2  = (const float*)d_in[18];
    const float* b_ff2  = (const float*)d_in[19];
    const float* ln2_g  = (const float*)d_in[20];
    const float* ln2_b  = (const float*)d_in[21];
    const float* hw1    = (const float*)d_in[22];
    const float* hb1    = (const float*)d_in[23];
    const float* hw2    = (const float*)d_in[24];
    const float* hb2    = (const float*)d_in[25];
    float* out = (float*)d_out;
    float* ws  = (float*)d_ws;

    float* z   = ws + WS_Z;
    short* wbf = (short*)(ws + WS_WBF);

    short* hbuf = (short*)(ws + WS_QKV);       // graph scratch aliases qkv region
    float* asb  = ws + WS_OBUF;
    float* adb  = ws + WS_OBUF + BT_ * 5 * 4;

    const int E = in_sizes[1] / 2;   // 20
    const int E2 = E + N_;           // 25

    // allow >64KB dynamic LDS for the mega kernel (idempotent, capture-safe)
    static bool attr_set = false;
    if (!attr_set) {
        hipFuncSetAttribute((const void*)layers_fused,
                            hipFuncAttributeMaxDynamicSharedMemorySize, MSMEM_BYTES);
        attr_set = true;
    }

    setup_kernel<<<1, 64, 0, stream>>>(ei, ws, E);
    prep_kernel<<<98, 256, 0, stream>>>(tw_qkv, tw_o, w_ff1, w_ff2, gat_w, wbf);
    gcn_h_mfma<<<BT_ / 16, 256, 0, stream>>>(x, gcn_w, gcn_b, a_src, a_dst, ws,
                                             wbf + WOFF_GATW, hbuf, asb, adb);
    gat_agg<<<BT_ / 4, 256, 0, stream>>>(hbuf, asb, adb, gat_b, gln_g, gln_b, ws, z, E2);
    layers_fused<<<B_, 512, MSMEM_BYTES, stream>>>(z, wbf, tb_qkv, tb_o,
                                                   ln1_g, ln1_b, b_ff1, b_ff2,
                                                   ln2_g, ln2_b, hw1, hb1, hw2, hb2, out);
}

// Round 10
// 287.032 us; speedup vs baseline: 1.2389x; 1.0091x over previous
//
#include <hip/hip_runtime.h>
#include <hip/hip_bf16.h>

// Problem constants (fixed by the reference)
#define B_  256
#define T_  72
#define N_  5
#define F_  10
#define D_  128
#define HH_ 4
#define CC_ 32
#define FF_ 256
#define BT_ (B_*T_)   // 18432
#define E2MAX 32

// ---------------- ws layout (float offsets) ----------------
#define WS_Z    256
#define WS_QKV  (WS_Z + BT_*D_)
#define WS_OBUF (WS_QKV + BT_*3*D_)
#define WS_WBF  (WS_OBUF + BT_*D_)      // bf16 weight region

// bf16 weight offsets (in shorts, from WS_WBF base)
#define WOFF_QKV(i)  ((i)*49152)                 // [384][128]
#define WOFF_O(i)    (147456 + (i)*16384)        // [128][128]
#define WOFF_FF1(i)  (196608 + (i)*32768)        // [256][128]
#define WOFF_FF2(i)  (294912 + (i)*32768)        // [128][256]
#define WOFF_GATW    393216                      // [128][64]

// ---------------- mega-kernel LDS carve (bytes) ----------------
#define MZF_OFF   0          // float [72][132]           38,016
#define MSB_OFF   38016      // short: z-bf16 [80][136] during QKV; P strips during attn; h1 at end
#define MSQ_OFF   70784      // short [80][136]  (s_f part 1)
#define MSK_OFF   92544      // short [80][136]  (s_f part 2)
#define MVT_OFF   114304     // short [128][104]; z1 bf16 aliases [80][136]
#define MOB_OFF   140928     // short [80][136]
#define MSMEM_BYTES 162688

typedef __attribute__((ext_vector_type(8))) short bf16x8;
typedef __attribute__((ext_vector_type(4))) float f32x4;

__device__ __forceinline__ unsigned short bf16_rne(float x) {
    unsigned u = __float_as_uint(x);
    unsigned r = (u + 0x7FFFu + ((u >> 16) & 1u)) >> 16;
    return (unsigned short)r;
}
__device__ __forceinline__ unsigned bf16pk(float a, float b) {
    return (unsigned)bf16_rne(a) | ((unsigned)bf16_rne(b) << 16);
}
__device__ __forceinline__ float bf2f(short s) {
    return __uint_as_float(((unsigned)(unsigned short)s) << 16);
}

// ---------------------------------------------------------------------------
__global__ void setup_kernel(const int* __restrict__ ei, float* __restrict__ ws, int E) {
    if (threadIdx.x != 0 || blockIdx.x != 0) return;
    int* wsi = (int*)ws;
    const int N = N_;
    int E2 = E + N;
    int src2[E2MAX], dst2[E2MAX];
    for (int e = 0; e < E; ++e) { src2[e] = ei[e]; dst2[e] = ei[E + e]; }
    for (int n = 0; n < N; ++n) { src2[E + n] = n; dst2[E + n] = n; }
    float A[N_ * N_];
    for (int i = 0; i < N * N; ++i) A[i] = 0.f;
    for (int e = 0; e < E2; ++e) A[dst2[e] * N + src2[e]] += 1.f;
    float dinv[N_];
    for (int n = 0; n < N; ++n) {
        float s = 0.f;
        for (int j = 0; j < N; ++j) s += A[n * N + j];
        dinv[n] = (s > 0.f) ? rsqrtf(s) : 0.f;
    }
    for (int n = 0; n < N; ++n)
        for (int j = 0; j < N; ++j)
            ws[n * N + j] = dinv[n] * A[n * N + j] * dinv[j];
    int cnt[N_];
    for (int n = 0; n < N; ++n) cnt[n] = 0;
    for (int e = 0; e < E2; ++e) cnt[dst2[e]]++;
    int off = 0;
    for (int n = 0; n < N; ++n) { wsi[96 + n] = off; off += cnt[n]; }
    wsi[96 + N] = off;
    int cur[N_];
    for (int n = 0; n < N; ++n) cur[n] = wsi[96 + n];
    for (int e = 0; e < E2; ++e) wsi[104 + cur[dst2[e]]++] = e;
    for (int e = 0; e < E2; ++e) { wsi[32 + e] = src2[e]; wsi[64 + e] = dst2[e]; }
}

// ---------------------------------------------------------------------------
// Weight prep: transpose R x C fp32 -> [C][R] bf16 into ws.
__global__ __launch_bounds__(256) void prep_kernel(
    const float* __restrict__ tw_qkv, const float* __restrict__ tw_o,
    const float* __restrict__ w_ff1, const float* __restrict__ w_ff2,
    const float* __restrict__ gat_w, short* __restrict__ wbf)
{
    __shared__ float s_t[64][65];
    const int tid = threadIdx.x;
    int t = blockIdx.x;
    const float* src; short* dst; int R, C, tr, tc;
    if (t >= 96) { int q = t - 96; src = gat_w; dst = wbf + WOFF_GATW; R = 64; C = 128; tr = 0; tc = q; }
    else {
        int layer = t / 32, r32 = t % 32;
        if (r32 < 12)      { src = tw_qkv + layer * (128*384); dst = wbf + WOFF_QKV(layer); R = 128; C = 384; tr = r32 / 6;  tc = r32 % 6; }
        else if (r32 < 16) { int q = r32 - 12; src = tw_o + layer * 16384; dst = wbf + WOFF_O(layer);  R = 128; C = 128; tr = q >> 1; tc = q & 1; }
        else if (r32 < 24) { int q = r32 - 16; src = w_ff1 + layer * 32768; dst = wbf + WOFF_FF1(layer); R = 128; C = 256; tr = q >> 2; tc = q & 3; }
        else               { int q = r32 - 24; src = w_ff2 + layer * 32768; dst = wbf + WOFF_FF2(layer); R = 256; C = 128; tr = q >> 1; tc = q & 1; }
    }
    #pragma unroll
    for (int it = 0; it < 16; ++it) {
        int e = it * 256 + tid;
        int r = e >> 6, c = e & 63;
        s_t[r][c] = src[(size_t)(tr*64 + r) * C + tc*64 + c];
    }
    __syncthreads();
    #pragma unroll
    for (int it = 0; it < 16; ++it) {
        int e = it * 256 + tid;
        int c = e >> 6, r = e & 63;
        dst[(size_t)(tc*64 + c) * R + tr*64 + r] = (short)bf16_rne(s_t[r][c]);
    }
}

// ---------------------------------------------------------------------------
__device__ __forceinline__ bf16x8 ld_frag(const short* s, int row, int kbase, int ldk) {
    return *(const bf16x8*)&s[row * ldk + (kbase ^ ((row & 7) << 3))];
}

// ---------------------------------------------------------------------------
// G1: x -> GCN(tanh) -> h = gcn @ gat_w (MFMA) -> h (bf16 global), a_s/a_d (global)
__global__ __launch_bounds__(256) void gcn_h_mfma(
    const float* __restrict__ x, const float* __restrict__ gcn_w, const float* __restrict__ gcn_b,
    const float* __restrict__ a_src, const float* __restrict__ a_dst,
    const float* __restrict__ ws, const short* __restrict__ gwT,
    short* __restrict__ hbuf, float* __restrict__ asb, float* __restrict__ adb)
{
    __shared__ float s_x[16 * 50];
    __shared__ float s_an[25];
    __shared__ short s_gcn[80 * 64];

    const int tid = threadIdx.x;
    const int tok0 = blockIdx.x * 16;

    for (int i = tid; i < 16 * 50; i += 256) s_x[i] = x[(size_t)tok0 * 50 + i];
    if (tid < 25) s_an[tid] = ws[tid];
    __syncthreads();

    #pragma unroll
    for (int it = 0; it < 2; ++it) {
        int idx = it * 256 + tid;
        int tl = idx >> 5, kp = idx & 31;
        int k0 = kp * 2;
        float w0[F_], w1[F_];
        #pragma unroll
        for (int f = 0; f < F_; ++f) { w0[f] = gcn_w[f * 64 + k0]; w1[f] = gcn_w[f * 64 + k0 + 1]; }
        float b0 = gcn_b[k0], b1 = gcn_b[k0 + 1];
        float xw0[N_], xw1[N_];
        #pragma unroll
        for (int n = 0; n < N_; ++n) {
            float a0 = b0, a1 = b1;
            #pragma unroll
            for (int f = 0; f < F_; ++f) {
                float xv = s_x[tl * 50 + n * 10 + f];
                a0 += xv * w0[f]; a1 += xv * w1[f];
            }
            xw0[n] = a0; xw1[n] = a1;
        }
        #pragma unroll
        for (int n = 0; n < N_; ++n) {
            float s0 = 0.f, s1 = 0.f;
            #pragma unroll
            for (int j = 0; j < N_; ++j) { float an = s_an[n * 5 + j]; s0 += an * xw0[j]; s1 += an * xw1[j]; }
            float e0 = __expf(2.f * fabsf(s0)), e1 = __expf(2.f * fabsf(s1));
            float t0 = copysignf(1.f - 2.f / (e0 + 1.f), s0);
            float t1 = copysignf(1.f - 2.f / (e1 + 1.f), s1);
            int row = tl * 5 + n;
            *(unsigned*)&s_gcn[row * 64 + (k0 ^ ((row & 7) << 3))] = bf16pk(t0, t1);
        }
    }
    __syncthreads();

    const int w = tid >> 6, lane = tid & 63;
    const int c = lane & 15, g = lane >> 4;
    const int kf = g * 8;
    bf16x8 bfr[2][2];
    #pragma unroll
    for (int nn = 0; nn < 2; ++nn)
        #pragma unroll
        for (int k0 = 0; k0 < 2; ++k0)
            bfr[nn][k0] = *(const bf16x8*)&gwT[(w * 32 + nn * 16 + c) * 64 + k0 * 32 + kf];
    const float as0 = a_src[w * 32 + c],      as1 = a_src[w * 32 + 16 + c];
    const float ad0 = a_dst[w * 32 + c],      ad1 = a_dst[w * 32 + 16 + c];
    #pragma unroll
    for (int m = 0; m < 5; ++m) {
        bf16x8 af0 = ld_frag(s_gcn, m * 16 + c, kf, 64);
        bf16x8 af1 = ld_frag(s_gcn, m * 16 + c, 32 + kf, 64);
        f32x4 a0 = {0,0,0,0}, a1 = {0,0,0,0};
        a0 = __builtin_amdgcn_mfma_f32_16x16x32_bf16(af0, bfr[0][0], a0, 0, 0, 0);
        a0 = __builtin_amdgcn_mfma_f32_16x16x32_bf16(af1, bfr[0][1], a0, 0, 0, 0);
        a1 = __builtin_amdgcn_mfma_f32_16x16x32_bf16(af0, bfr[1][0], a1, 0, 0, 0);
        a1 = __builtin_amdgcn_mfma_f32_16x16x32_bf16(af1, bfr[1][1], a1, 0, 0, 0);
        float ps[4], pd[4];
        #pragma unroll
        for (int i = 0; i < 4; ++i) {
            int row = m * 16 + g * 4 + i;
            size_t gr = (size_t)(tok0 * 5 + row) * 128;
            hbuf[gr + w * 32 + c]      = (short)bf16_rne(a0[i]);
            hbuf[gr + w * 32 + 16 + c] = (short)bf16_rne(a1[i]);
            ps[i] = a0[i] * as0 + a1[i] * as1;
            pd[i] = a0[i] * ad0 + a1[i] * ad1;
        }
        #pragma unroll
        for (int mm = 1; mm < 16; mm <<= 1)
            #pragma unroll
            for (int i = 0; i < 4; ++i) { ps[i] += __shfl_xor(ps[i], mm); pd[i] += __shfl_xor(pd[i], mm); }
        if (c == 0) {
            #pragma unroll
            for (int i = 0; i < 4; ++i) {
                int row = m * 16 + g * 4 + i;
                asb[(size_t)(tok0 * 5 + row) * 4 + w] = ps[i];
                adb[(size_t)(tok0 * 5 + row) * 4 + w] = pd[i];
            }
        }
    }
}

// ---------------------------------------------------------------------------
// G2: alpha softmax + aggregate + gat_b + LN + mean + PE -> z
__global__ __launch_bounds__(256) void gat_agg(
    const short* __restrict__ hbuf, const float* __restrict__ asb, const float* __restrict__ adb,
    const float* __restrict__ gat_b, const float* __restrict__ gln_g, const float* __restrict__ gln_b,
    const float* __restrict__ ws, float* __restrict__ z, int E2)
{
    __shared__ int   s_src[E2MAX], s_csr_off[N_ + 1], s_csr_e[E2MAX];
    __shared__ float s_alpha[4][E2MAX][4];
    __shared__ short s_h[4 * 5 * 128];
    __shared__ float s_asl[4][N_][4], s_adl[4][N_][4];   // staged a_s / a_d

    const int tid = threadIdx.x;
    const int wv = tid >> 6, lane = tid & 63;
    const int tok = blockIdx.x * 4 + wv;
    const int* wsi = (const int*)ws;

    if (tid < E2) { s_src[tid] = wsi[32 + tid]; s_csr_e[tid] = wsi[104 + tid]; }
    if (tid < N_ + 1) s_csr_off[tid] = wsi[96 + tid];
    if (tid >= 64 && tid < 144) ((float*)s_asl)[tid - 64] = asb[(size_t)blockIdx.x * 80 + tid - 64];
    if (tid >= 144 && tid < 224) ((float*)s_adl)[tid - 144] = adb[(size_t)blockIdx.x * 80 + tid - 144];
    {
        const uint4* hb4 = (const uint4*)(hbuf + (size_t)blockIdx.x * 4 * 5 * 128);
        uint4* sh4 = (uint4*)s_h;
        #pragma unroll
        for (int it = 0; it < 2; ++it) {
            int i = it * 256 + tid;
            if (i < 320) sh4[i] = hb4[i];
        }
    }
    __syncthreads();

    if (lane < 20) {
        int dn = lane >> 2, head = lane & 3;
        int j0 = s_csr_off[dn], j1 = s_csr_off[dn + 1];
        float adv = s_adl[wv][dn][head];
        float mx = -1e30f;
        for (int j = j0; j < j1; ++j) {
            int e = s_csr_e[j];
            float ev = s_asl[wv][s_src[e]][head] + adv;
            ev = ev > 0.f ? ev : 0.2f * ev;
            mx = fmaxf(mx, ev);
        }
        float den = 0.f;
        for (int j = j0; j < j1; ++j) {
            int e = s_csr_e[j];
            float ev = s_asl[wv][s_src[e]][head] + adv;
            ev = ev > 0.f ? ev : 0.2f * ev;
            float ex = __expf(ev - mx);
            den += ex;
            s_alpha[wv][e][head] = ex;
        }
        float r = 1.f / den;
        for (int j = j0; j < j1; ++j) s_alpha[wv][s_csr_e[j]][head] *= r;
    }
    __syncthreads();

    const int h0 = lane >> 5, h1 = 2 + (lane >> 5);
    const float gb0 = gat_b[lane],      gb1 = gat_b[lane + 64];
    const float gg0 = gln_g[lane],      gg1 = gln_g[lane + 64];
    const float gB0 = gln_b[lane],      gB1 = gln_b[lane + 64];
    float v0[N_], v1[N_];
    #pragma unroll
    for (int n = 0; n < N_; ++n) {
        float a0 = 0.f, a1 = 0.f;
        int j0 = s_csr_off[n], j1 = s_csr_off[n + 1];
        for (int j = j0; j < j1; ++j) {
            int e = s_csr_e[j];
            int rb = (wv * 5 + s_src[e]) * 128;
            a0 += s_alpha[wv][e][h0] * bf2f(s_h[rb + lane]);
            a1 += s_alpha[wv][e][h1] * bf2f(s_h[rb + lane + 64]);
        }
        v0[n] = a0 + gb0; v1[n] = a1 + gb1;
    }
    float r1[N_], r2[N_];
    #pragma unroll
    for (int n = 0; n < N_; ++n) { r1[n] = v0[n] + v1[n]; r2[n] = v0[n]*v0[n] + v1[n]*v1[n]; }
    #pragma unroll
    for (int mm = 1; mm < 64; mm <<= 1)
        #pragma unroll
        for (int n = 0; n < N_; ++n) { r1[n] += __shfl_xor(r1[n], mm); r2[n] += __shfl_xor(r2[n], mm); }
    float z0 = 0.f, z1 = 0.f;
    #pragma unroll
    for (int n = 0; n < N_; ++n) {
        float mu = r1[n] * (1.f / D_);
        float var = r2[n] * (1.f / D_) - mu * mu;
        float rstd = rsqrtf(var + 1e-5f);
        z0 += (v0[n] - mu) * rstd * gg0 + gB0;
        z1 += (v1[n] - mu) * rstd * gg1 + gB1;
    }
    z0 *= (1.f / N_); z1 *= (1.f / N_);
    const float cpe = -9.210340371976184f / (float)D_;
    int t = tok % T_;
    float dv0 = __expf((float)(lane & ~1) * cpe);
    float dv1 = __expf((float)((lane + 64) & ~1) * cpe);
    float ang0 = (float)t * dv0, ang1 = (float)t * dv1;
    z0 += (lane & 1) ? __cosf(ang0) : __sinf(ang0);
    z1 += (lane & 1) ? __cosf(ang1) : __sinf(ang1);
    z[(size_t)tok * D_ + lane] = z0;
    z[(size_t)tok * D_ + 64 + lane] = z1;
}

// ---------------------------------------------------------------------------
// MEGA v3: all 3 layers + heads. Direct-global weight fragments (L2-hot),
// z-bf16 resident in s_b, 5 barriers/layer. 512 threads = 2 waves/SIMD.
__global__ __launch_bounds__(512, 1) void layers_fused(
    const float* __restrict__ zg, const short* __restrict__ wbf,
    const float* __restrict__ tb_qkv, const float* __restrict__ tb_o,
    const float* __restrict__ ln1_g, const float* __restrict__ ln1_b,
    const float* __restrict__ b_ff1, const float* __restrict__ b_ff2,
    const float* __restrict__ ln2_g, const float* __restrict__ ln2_b,
    const float* __restrict__ hw1, const float* __restrict__ hb1,
    const float* __restrict__ hw2, const float* __restrict__ hb2,
    float* __restrict__ out)
{
    extern __shared__ char smem[];
    float* s_zf = (float*)(smem + MZF_OFF);          // [72][132] fp32 z
    short* s_b  = (short*)(smem + MSB_OFF);          // z-bf16 [80][136] / P strips / h1
    short* s_q  = (short*)(smem + MSQ_OFF);          // [80][136]
    short* s_k  = (short*)(smem + MSK_OFF);          // [80][136]
    short* s_vt = (short*)(smem + MVT_OFF);          // [128][104]; z1 bf16 aliases
    short* s_ob = (short*)(smem + MOB_OFF);          // [80][136]
    short* s_f  = s_q;                               // [80][264]
    short* s_z1 = s_vt;                              // [80][136]

    const int tid = threadIdx.x;
    const int w = tid >> 6, lane = tid & 63;         // w = 0..7
    const int c = lane & 15, g = lane >> 4;
    const int kf = g * 8;
    const int b = blockIdx.x;

    // ---- init: load z -> s_zf fp32 + s_b bf16; zero pads
    for (int idx = tid; idx < 72 * 64; idx += 512) {
        int r = idx >> 6, c2 = (idx & 63) * 2;
        float2 v = *(const float2*)&zg[(size_t)(b * T_ + r) * D_ + c2];
        s_zf[r * 132 + c2]     = v.x;
        s_zf[r * 132 + c2 + 1] = v.y;
        *(unsigned*)&s_b[r * 136 + c2] = bf16pk(v.x, v.y);
    }
    {   // zero z-bf16 pad rows 72..79 (128 cols = 64 uints per row)
        int r = 72 + (tid >> 6), cc = (tid & 63) * 2;
        *(unsigned*)&s_b[r * 136 + cc] = 0;
    }
    for (int idx = tid; idx < 128 * 16; idx += 512) {  // zero V^T keys 72..103
        int chn = idx >> 4, key = 72 + (idx & 15) * 2;
        *(unsigned*)&s_vt[chn * 104 + key] = 0;
    }
    __syncthreads();

    for (int L = 0; L < 3; ++L) {
        const short* Wq = wbf + WOFF_QKV(L);
        const short* Wo = wbf + WOFF_O(L);
        const short* W1 = wbf + WOFF_FF1(L);
        const short* W2 = wbf + WOFF_FF2(L);
        const float* bq = tb_qkv + L * 384;
        const float* bo = tb_o + L * D_;
        const float* g1 = ln1_g + L * D_, *be1 = ln1_b + L * D_;
        const float* b1 = b_ff1 + L * FF_, *b2 = b_ff2 + L * D_;
        const float* g2 = ln2_g + L * D_, *be2 = ln2_b + L * D_;

        // ====== QKV: wave owns col group n0 = w; all 3 chunks, no staging ======
        {
            const int wcol = w * 16 + c;
            bf16x8 Bf[3][4];
            float bv[3];
            #pragma unroll
            for (int ch = 0; ch < 3; ++ch) {
                const short* Wc = Wq + (size_t)(ch * 128 + wcol) * 128;
                #pragma unroll
                for (int k0 = 0; k0 < 4; ++k0) Bf[ch][k0] = *(const bf16x8*)&Wc[k0 * 32 + kf];
                bv[ch] = bq[ch * 128 + wcol];
            }
            #pragma unroll
            for (int m = 0; m < 5; ++m) {
                bf16x8 Af[4];
                #pragma unroll
                for (int k0 = 0; k0 < 4; ++k0)
                    Af[k0] = *(const bf16x8*)&s_b[(m * 16 + c) * 136 + k0 * 32 + kf];
                f32x4 aq = {bv[0], bv[0], bv[0], bv[0]};
                f32x4 ak = {bv[1], bv[1], bv[1], bv[1]};
                f32x4 av = {bv[2], bv[2], bv[2], bv[2]};
                #pragma unroll
                for (int k0 = 0; k0 < 4; ++k0) {
                    aq = __builtin_amdgcn_mfma_f32_16x16x32_bf16(Af[k0], Bf[0][k0], aq, 0, 0, 0);
                    ak = __builtin_amdgcn_mfma_f32_16x16x32_bf16(Af[k0], Bf[1][k0], ak, 0, 0, 0);
                    av = __builtin_amdgcn_mfma_f32_16x16x32_bf16(Af[k0], Bf[2][k0], av, 0, 0, 0);
                }
                #pragma unroll
                for (int i = 0; i < 4; ++i) {
                    int lrow = m * 16 + g * 4 + i;
                    s_q[lrow * 136 + wcol]  = (short)bf16_rne(aq[i]);
                    s_k[lrow * 136 + wcol]  = (short)bf16_rne(ak[i]);
                    s_vt[wcol * 104 + lrow] = (short)bf16_rne(av[i]);
                }
            }
        }
        __syncthreads();

        // ====== ATTENTION: wave w -> head w&3, m-range by w>>2 ======
        {
            short* pstrip = s_b + w * (16 * 104);   // z-bf16 dead; 8 strips = 26,624 B
            for (int t2 = lane; t2 < 16 * 24; t2 += 64) {
                int r = t2 / 24, col = 80 + (t2 % 24);
                pstrip[r * 104 + col] = 0;
            }
            const int h = w & 3;
            const int mlo = (w >> 2) ? 3 : 0;
            const int mhi = (w >> 2) ? 5 : 3;
            const float scale = 0.17677669529663687f;
            for (int m = mlo; m < mhi; ++m) {
                bf16x8 aq = *(const bf16x8*)&s_q[(m * 16 + c) * 136 + h * 32 + kf];
                float ps[5][4], mx[4], den[4];
                #pragma unroll
                for (int i = 0; i < 4; ++i) mx[i] = -1e30f;
                #pragma unroll
                for (int n0 = 0; n0 < 5; ++n0) {
                    bf16x8 bk = *(const bf16x8*)&s_k[(n0 * 16 + c) * 136 + h * 32 + kf];
                    f32x4 z4 = {0,0,0,0};
                    f32x4 accS = __builtin_amdgcn_mfma_f32_16x16x32_bf16(aq, bk, z4, 0, 0, 0);
                    #pragma unroll
                    for (int i = 0; i < 4; ++i) {
                        float s = accS[i] * scale;
                        if (n0 == 4 && c >= 8) s = -1e30f;
                        ps[n0][i] = s;
                        mx[i] = fmaxf(mx[i], s);
                    }
                }
                #pragma unroll
                for (int mm = 1; mm < 16; mm <<= 1)
                    #pragma unroll
                    for (int i = 0; i < 4; ++i) mx[i] = fmaxf(mx[i], __shfl_xor(mx[i], mm));
                #pragma unroll
                for (int i = 0; i < 4; ++i) den[i] = 0.f;
                #pragma unroll
                for (int n0 = 0; n0 < 5; ++n0)
                    #pragma unroll
                    for (int i = 0; i < 4; ++i) { float e = __expf(ps[n0][i] - mx[i]); ps[n0][i] = e; den[i] += e; }
                #pragma unroll
                for (int mm = 1; mm < 16; mm <<= 1)
                    #pragma unroll
                    for (int i = 0; i < 4; ++i) den[i] += __shfl_xor(den[i], mm);
                float rden[4];
                #pragma unroll
                for (int i = 0; i < 4; ++i) rden[i] = 1.f / den[i];
                #pragma unroll
                for (int n0 = 0; n0 < 5; ++n0)
                    #pragma unroll
                    for (int i = 0; i < 4; ++i)
                        pstrip[(g * 4 + i) * 104 + n0 * 16 + c] = (short)bf16_rne(ps[n0][i] * rden[i]);
                f32x4 accO[2] = {{0,0,0,0},{0,0,0,0}};
                #pragma unroll
                for (int kt = 0; kt < 3; ++kt) {
                    bf16x8 ap = *(const bf16x8*)&pstrip[c * 104 + kt * 32 + kf];
                    #pragma unroll
                    for (int n0 = 0; n0 < 2; ++n0) {
                        bf16x8 bv = *(const bf16x8*)&s_vt[(h * 32 + n0 * 16 + c) * 104 + kt * 32 + kf];
                        accO[n0] = __builtin_amdgcn_mfma_f32_16x16x32_bf16(ap, bv, accO[n0], 0, 0, 0);
                    }
                }
                #pragma unroll
                for (int n0 = 0; n0 < 2; ++n0)
                    #pragma unroll
                    for (int i = 0; i < 4; ++i)
                        s_ob[(m * 16 + g * 4 + i) * 136 + h * 32 + n0 * 16 + c] = (short)bf16_rne(accO[n0][i]);
            }
        }
        __syncthreads();

        // ====== O-PROJ + LN1 (waves 0..4 own m = w) ======
        if (w < 5) {
            const int m = w;
            bf16x8 Af[4];
            #pragma unroll
            for (int k0 = 0; k0 < 4; ++k0)
                Af[k0] = *(const bf16x8*)&s_ob[(m * 16 + c) * 136 + k0 * 32 + kf];
            f32x4 acc[8];
            #pragma unroll
            for (int n0 = 0; n0 < 8; ++n0) {
                const short* Wp = Wo + (size_t)(n0 * 16 + c) * 128;
                float bvv = bo[n0 * 16 + c];
                f32x4 a = {bvv, bvv, bvv, bvv};
                #pragma unroll
                for (int k0 = 0; k0 < 4; ++k0) {
                    bf16x8 bfg = *(const bf16x8*)&Wp[k0 * 32 + kf];
                    a = __builtin_amdgcn_mfma_f32_16x16x32_bf16(Af[k0], bfg, a, 0, 0, 0);
                }
                acc[n0] = a;
            }
            #pragma unroll
            for (int n0 = 0; n0 < 8; ++n0)
                #pragma unroll
                for (int i = 0; i < 4; ++i) {
                    int row = m * 16 + g * 4 + i;
                    acc[n0][i] += (row < 72) ? s_zf[row * 132 + n0 * 16 + c] : 0.f;
                }
            float s1[4] = {0,0,0,0}, s2[4] = {0,0,0,0};
            #pragma unroll
            for (int n0 = 0; n0 < 8; ++n0)
                #pragma unroll
                for (int i = 0; i < 4; ++i) { float v = acc[n0][i]; s1[i] += v; s2[i] += v * v; }
            #pragma unroll
            for (int mm = 1; mm < 16; mm <<= 1)
                #pragma unroll
                for (int i = 0; i < 4; ++i) { s1[i] += __shfl_xor(s1[i], mm); s2[i] += __shfl_xor(s2[i], mm); }
            #pragma unroll
            for (int i = 0; i < 4; ++i) {
                float mu = s1[i] * (1.f / D_);
                float var = s2[i] * (1.f / D_) - mu * mu;
                float rstd = rsqrtf(var + 1e-5f);
                int row = m * 16 + g * 4 + i;
                #pragma unroll
                for (int n0 = 0; n0 < 8; ++n0) {
                    float v = (acc[n0][i] - mu) * rstd * g1[n0 * 16 + c] + be1[n0 * 16 + c];
                    if (row < 72) s_zf[row * 132 + n0 * 16 + c] = v;
                    s_z1[row * 136 + n0 * 16 + c] = (short)bf16_rne(v);
                }
            }
        }
        __syncthreads();

        // ====== FF1 (wave owns n0 = w; both chunks, no staging) ======
        {
            const int wcol = w * 16 + c;
            #pragma unroll
            for (int ch = 0; ch < 2; ++ch) {
                const short* Wp = W1 + (size_t)(ch * 128 + wcol) * 128;
                bf16x8 Bf[4];
                #pragma unroll
                for (int k0 = 0; k0 < 4; ++k0) Bf[k0] = *(const bf16x8*)&Wp[k0 * 32 + kf];
                const float bvv = b1[ch * 128 + wcol];
                #pragma unroll
                for (int m = 0; m < 5; ++m) {
                    bf16x8 Af[4];
                    #pragma unroll
                    for (int k0 = 0; k0 < 4; ++k0)
                        Af[k0] = *(const bf16x8*)&s_z1[(m * 16 + c) * 136 + k0 * 32 + kf];
                    f32x4 a = {bvv, bvv, bvv, bvv};
                    #pragma unroll
                    for (int k0 = 0; k0 < 4; ++k0)
                        a = __builtin_amdgcn_mfma_f32_16x16x32_bf16(Af[k0], Bf[k0], a, 0, 0, 0);
                    #pragma unroll
                    for (int i = 0; i < 4; ++i) {
                        int lrow = m * 16 + g * 4 + i;
                        s_f[lrow * 264 + ch * 128 + wcol] = (short)bf16_rne(fmaxf(a[i], 0.f));
                    }
                }
            }
        }
        __syncthreads();

        // ====== FF2 + LN2 + z-bf16 refresh (waves 0..4 own m = w; w>=5 zero pads) ======
        if (w < 5) {
            const int m = w;
            f32x4 acc2[8];
            #pragma unroll
            for (int n0 = 0; n0 < 8; ++n0) {
                float bvv = b2[n0 * 16 + c];
                acc2[n0] = (f32x4){bvv, bvv, bvv, bvv};
            }
            #pragma unroll
            for (int kc = 0; kc < 2; ++kc) {
                bf16x8 Af[4];
                #pragma unroll
                for (int k0 = 0; k0 < 4; ++k0)
                    Af[k0] = *(const bf16x8*)&s_f[(m * 16 + c) * 264 + kc * 128 + k0 * 32 + kf];
                #pragma unroll
                for (int n0 = 0; n0 < 8; ++n0) {
                    const short* Wp = W2 + (size_t)(n0 * 16 + c) * 256 + kc * 128;
                    #pragma unroll
                    for (int k0 = 0; k0 < 4; ++k0) {
                        bf16x8 bfg = *(const bf16x8*)&Wp[k0 * 32 + kf];
                        acc2[n0] = __builtin_amdgcn_mfma_f32_16x16x32_bf16(Af[k0], bfg, acc2[n0], 0, 0, 0);
                    }
                }
            }
            #pragma unroll
            for (int n0 = 0; n0 < 8; ++n0)
                #pragma unroll
                for (int i = 0; i < 4; ++i) {
                    int row = m * 16 + g * 4 + i;
                    acc2[n0][i] += (row < 72) ? s_zf[row * 132 + n0 * 16 + c] : 0.f;
                }
            float s1[4] = {0,0,0,0}, s2[4] = {0,0,0,0};
            #pragma unroll
            for (int n0 = 0; n0 < 8; ++n0)
                #pragma unroll
                for (int i = 0; i < 4; ++i) { float v = acc2[n0][i]; s1[i] += v; s2[i] += v * v; }
            #pragma unroll
            for (int mm = 1; mm < 16; mm <<= 1)
                #pragma unroll
                for (int i = 0; i < 4; ++i) { s1[i] += __shfl_xor(s1[i], mm); s2[i] += __shfl_xor(s2[i], mm); }
            #pragma unroll
            for (int i = 0; i < 4; ++i) {
                float mu = s1[i] * (1.f / D_);
                float var = s2[i] * (1.f / D_) - mu * mu;
                float rstd = rsqrtf(var + 1e-5f);
                int row = m * 16 + g * 4 + i;
                if (row < 72) {
                    #pragma unroll
                    for (int n0 = 0; n0 < 8; ++n0) {
                        float v = (acc2[n0][i] - mu) * rstd * g2[n0 * 16 + c] + be2[n0 * 16 + c];
                        s_zf[row * 132 + n0 * 16 + c] = v;
                        s_b[row * 136 + n0 * 16 + c] = (short)bf16_rne(v);  // z-bf16 for next QKV
                    }
                }
            }
        } else {
            // zero z-bf16 pad rows 72..79 (P strips dead; LN2 writers touch rows < 72 only)
            int wl = (w - 5) * 64 + lane;   // 0..191
            for (int i = wl; i < 512; i += 192) {
                int r = 72 + (i >> 6), cc = (i & 63) * 2;
                *(unsigned*)&s_b[r * 136 + cc] = 0;
            }
        }
        __syncthreads();
    }

    // ====== HEADS (token 71 only) ======
    float* s_h1 = (float*)s_b;   // [6][64]
    for (int t2 = tid; t2 < 384; t2 += 512) {
        int k = t2 >> 6, j = t2 & 63;
        float acc = hb1[k * 64 + j];
        const float* w1p = hw1 + (size_t)k * D_ * 64 + j;
        for (int d = 0; d < D_; ++d) acc += s_zf[71 * 132 + d] * w1p[d * 64];
        s_h1[k * 64 + j] = fmaxf(acc, 0.f);
    }
    __syncthreads();
    if (tid < 30) {
        int k = tid / 5, s = tid % 5;
        float o = hb2[k * 5 + s];
        const float* w2p = hw2 + (size_t)k * 64 * 5 + s;
        for (int j = 0; j < 64; ++j) o += s_h1[k * 64 + j] * w2p[j * 5];
        out[(size_t)k * (B_ * 5) + b * 5 + s] = o;
    }
}

// ---------------------------------------------------------------------------
extern "C" void kernel_launch(void* const* d_in, const int* in_sizes, int n_in,
                              void* d_out, int out_size, void* d_ws, size_t ws_size,
                              hipStream_t stream) {
    const float* x      = (const float*)d_in[0];
    const int*   ei     = (const int*)  d_in[1];
    const float* gcn_w  = (const float*)d_in[2];
    const float* gcn_b  = (const float*)d_in[3];
    const float* gat_w  = (const float*)d_in[4];
    const float* a_src  = (const float*)d_in[5];
    const float* a_dst  = (const float*)d_in[6];
    const float* gat_b  = (const float*)d_in[7];
    const float* gln_g  = (const float*)d_in[8];
    const float* gln_b  = (const float*)d_in[9];
    const float* tw_qkv = (const float*)d_in[10];
    const float* tb_qkv = (const float*)d_in[11];
    const float* tw_o   = (const float*)d_in[12];
    const float* tb_o   = (const float*)d_in[13];
    const float* ln1_g  = (const float*)d_in[14];
    const float* ln1_b  = (const float*)d_in[15];
    const float* w_ff1  = (const float*)d_in[16];
    const float* b_ff1  = (const float*)d_in[17];
    const float* w_ff2  = (const float*)d_in[18];
    const float* b_ff2  = (const float*)d_in[19];
    const float* ln2_g  = (const float*)d_in[20];
    const float* ln2_b  = (const float*)d_in[21];
    const float* hw1    = (const float*)d_in[22];
    const float* hb1    = (const float*)d_in[23];
    const float* hw2    = (const float*)d_in[24];
    const float* hb2    = (const float*)d_in[25];
    float* out = (float*)d_out;
    float* ws  = (float*)d_ws;

    float* z   = ws + WS_Z;
    short* wbf = (short*)(ws + WS_WBF);

    short* hbuf = (short*)(ws + WS_QKV);       // graph scratch aliases qkv region
    float* asb  = ws + WS_OBUF;
    float* adb  = ws + WS_OBUF + BT_ * 5 * 4;

    const int E = in_sizes[1] / 2;   // 20
    const int E2 = E + N_;           // 25

    // allow >64KB dynamic LDS for the mega kernel (idempotent, capture-safe)
    static bool attr_set = false;
    if (!attr_set) {
        hipFuncSetAttribute((const void*)layers_fused,
                            hipFuncAttributeMaxDynamicSharedMemorySize, MSMEM_BYTES);
        attr_set = true;
    }

    setup_kernel<<<1, 64, 0, stream>>>(ei, ws, E);
    prep_kernel<<<98, 256, 0, stream>>>(tw_qkv, tw_o, w_ff1, w_ff2, gat_w, wbf);
    gcn_h_mfma<<<BT_ / 16, 256, 0, stream>>>(x, gcn_w, gcn_b, a_src, a_dst, ws,
                                             wbf + WOFF_GATW, hbuf, asb, adb);
    gat_agg<<<BT_ / 4, 256, 0, stream>>>(hbuf, asb, adb, gat_b, gln_g, gln_b, ws, z, E2);
    layers_fused<<<B_, 512, MSMEM_BYTES, stream>>>(z, wbf, tb_qkv, tb_o,
                                                   ln1_g, ln1_b, b_ff1, b_ff2,
                                                   ln2_g, ln2_b, hw1, hb1, hw2, hb2, out);
}